// Round 5
// baseline (684.042 us; speedup 1.0000x reference)
//
#include <hip/hip_runtime.h>
#include <cfloat>

// VQ-VAE vector quantizer. Round 10: r9 never launched -- 72 KB dynamic LDS
// exceeds the 64 KB default cap; the launch needs a one-time
// hipFuncSetAttribute(MaxDynamicSharedMemorySize) opt-in (graph-capture safe,
// host-side). Schedule identical to r9: triple-buffered LDS, raw s_barrier,
// counted "s_waitcnt vmcnt(6)" -> depth-2 prefetch, loads in flight ACROSS
// barriers (r8 proved __syncthreads' vmcnt(0) drain is the 43%-MfmaUtil stall).
// N=32768 rows, K=8192 codes, D=256.
#define K_CODES 8192
#define DIM     256
#define NROWS   32768

// d_out float offsets (outputs concatenated in reference return order)
#define O_ZQ    0
#define O_LOSS  8388608
#define O_IDX   8388609
#define O_NEMB  8421377
#define O_NCS   10518529
#define O_NEMAW 10526721

// ---- MFMA path params
#define NCH          2                    // code chunks
#define CODES_PER_CH (K_CODES / NCH)      // 4096
#define NT_TILES     (CODES_PER_CH / 256) // 16
#define BUF_U        12288                // ushorts per buffer: A 4096 + B 8192
#define STEPS_NT     24                   // BK=32 steps per nt (768/32)
#define LDS_BYTES    (3 * BUF_U * 2)      // 73728

typedef __attribute__((ext_vector_type(8))) short short8;
typedef __attribute__((ext_vector_type(4))) float floatx4;

__device__ __forceinline__ unsigned short f2bf_rne(float x) {
    unsigned u = __float_as_uint(x);
    u += 0x7fffu + ((u >> 16) & 1u);
    return (unsigned short)(u >> 16);
}
__device__ __forceinline__ float bf2f(unsigned short h) {
    return __uint_as_float(((unsigned)h) << 16);
}
__device__ __forceinline__ void async16(const void* g, void* l) {
    __builtin_amdgcn_global_load_lds(
        (const __attribute__((address_space(1))) void*)g,
        (__attribute__((address_space(3))) void*)l, 16, 0, 0);
}

// ---------------------------------------------------------------- fused convert: z & emb -> {hi,lo} bf16 + |e|^2 + zero
__global__ void k_prep(const float* __restrict__ z, const float* __restrict__ emb,
                       unsigned short* __restrict__ zcat, unsigned short* __restrict__ ecat,
                       float* __restrict__ esq, int* __restrict__ zero16k) {
    const int b = blockIdx.x;
    if (b < 8192) {
        const int i = b * 256 + threadIdx.x;         // float4 idx, 2,097,152
        const int row = i >> 6;
        const int col = (i & 63) << 2;
        float4 v = ((const float4*)z)[i];
        // fold -2 into z: bf16(-2z) == -2*bf16(z) exactly (pow2 scale)
        float nx = -2.0f * v.x, ny = -2.0f * v.y, nz = -2.0f * v.z, nw = -2.0f * v.w;
        ushort4 h, l;
        h.x = f2bf_rne(nx); l.x = f2bf_rne(nx - bf2f(h.x));
        h.y = f2bf_rne(ny); l.y = f2bf_rne(ny - bf2f(h.y));
        h.z = f2bf_rne(nz); l.z = f2bf_rne(nz - bf2f(h.z));
        h.w = f2bf_rne(nw); l.w = f2bf_rne(nw - bf2f(h.w));
        *(ushort4*)&zcat[(size_t)row * 512 + col]       = h;
        *(ushort4*)&zcat[(size_t)row * 512 + 256 + col] = l;
    } else {
        const int gid  = (b - 8192) * 256 + threadIdx.x;  // 0..524287
        if (gid < 2 * K_CODES) zero16k[gid] = 0;          // counts + cursor
        const int code = gid >> 6;
        const int lane = gid & 63;
        const int col  = lane << 2;
        float4 v = ((const float4*)emb)[code * 64 + lane];
        ushort4 h, l;
        h.x = f2bf_rne(v.x); l.x = f2bf_rne(v.x - bf2f(h.x));
        h.y = f2bf_rne(v.y); l.y = f2bf_rne(v.y - bf2f(h.y));
        h.z = f2bf_rne(v.z); l.z = f2bf_rne(v.z - bf2f(h.z));
        h.w = f2bf_rne(v.w); l.w = f2bf_rne(v.w - bf2f(h.w));
        *(ushort4*)&ecat[(size_t)code * 512 + col]       = h;
        *(ushort4*)&ecat[(size_t)code * 512 + 256 + col] = l;
        float s = fmaf(v.x, v.x, fmaf(v.y, v.y, fmaf(v.z, v.z, v.w * v.w)));
#pragma unroll
        for (int off = 32; off > 0; off >>= 1) s += __shfl_down(s, off, 64);
        if (lane == 0) esq[code] = s;
    }
}

// ---------------------------------------------------------------- MFMA argmin GEMM (virtual K=768, BK=32, 128x256 tile)
// score(n,k) = esq[k] + dot(zcat_n, ecat_k segs), zcat encodes -2z.
// A segs {hi,hi,lo}: off_a=(k0&255)|((k0&512)>>1); B segs {hi,lo,hi}: off_b=k0&511.
// Triple-buffered counted-vmcnt pipeline, one raw s_barrier per 32-K step:
//   [vmcnt(6): own stage(g) landed, stage(g+1) stays in flight]
//   [s_barrier: all waves' stage(g) landed AND all finished compute(g-1)]
//   [STAGE(g+2): overwrites buf last read at compute(g-1) -- safe post-barrier]
//   [COMPUTE(g)]
// Depth-2 prefetch window ~= 2 compute phases (+ per-nt epilogue VALU).
// LDS layout (BK=32, 64B rows of 4x16B chunks): logical chunk c of row R at
// physical chunk c ^ ((R>>1)&3); conflict-free (verified r6-r8: 0 conflicts).
// Stage pre-swizzles the GLOBAL source (linear LDS dest per global_load_lds).
// 4 waves, wave-tile 64x128: wrow=(w>>1)*64, wcol=(w&1)*128, acc 4x8 of 16x16x32.
#define STAGE3(obufU, BGP, offa, offb)                                          \
    do {                                                                        \
        _Pragma("unroll")                                                       \
        for (int c_ = 0; c_ < 6; ++c_) {                                        \
            const int u_ = w * 6 + c_;                                          \
            if (u_ < 8)                                                         \
                async16(aGlob + (size_t)u_ * 8192 + (offa),                     \
                        &s_all[(obufU) + u_ * 512]);                            \
            else                                                                \
                async16((BGP) + (size_t)(u_ - 8) * 8192 + (offb),               \
                        &s_all[(obufU) + 4096 + (u_ - 8) * 512]);               \
        }                                                                       \
    } while (0)

// B fragments resident (32 VGPR), A streamed one at a time (4 VGPR).
#define COMPUTE3(obufU)                                                         \
    do {                                                                        \
        short8 bf_[8];                                                          \
        _Pragma("unroll")                                                       \
        for (int j_ = 0; j_ < 8; ++j_)                                          \
            bf_[j_] = *(const short8*)                                          \
                &s_all[(obufU) + 4096 + (wcol + j_ * 16 + m) * 32 + xo];        \
        _Pragma("unroll")                                                       \
        for (int i_ = 0; i_ < 4; ++i_) {                                        \
            const short8 af_ = *(const short8*)                                 \
                &s_all[(obufU) + (wrow + i_ * 16 + m) * 32 + xo];               \
            _Pragma("unroll")                                                   \
            for (int j_ = 0; j_ < 8; ++j_)                                      \
                acc[i_][j_] = __builtin_amdgcn_mfma_f32_16x16x32_bf16(          \
                    af_, bf_[j_], acc[i_][j_], 0, 0, 0);                        \
        }                                                                       \
    } while (0)

__global__ __launch_bounds__(256, 2) void k_argmin_mfma(
        const unsigned short* __restrict__ zcat, const unsigned short* __restrict__ ecat,
        const float* __restrict__ esq,
        float* __restrict__ part_v, int* __restrict__ part_i) {
    // 3 buffers x (A 8 KB + B 16 KB) = 72 KB dynamic LDS (opt-in via
    // hipFuncSetAttribute in kernel_launch; 2 blocks/CU x 72 KB = 144 <= 160)
    extern __shared__ __align__(16) unsigned short s_all[];
    const int t    = threadIdx.x;
    const int w    = t >> 6;
    const int lane = t & 63;
    const int quad = lane >> 4;
    const int m    = lane & 15;
    const int wrow = (w >> 1) * 64;
    const int wcol = (w & 1) * 128;
    const int row0   = blockIdx.x * 128;
    const int cbase0 = blockIdx.y * CODES_PER_CH;

    // staging geometry: 1536 16B slots/step (512 A + 1024 B) = 24 wave-chunks
    // of 64 slots; wave w takes u = w*6..w*6+5 (u<8 -> A rows u*16.., else B
    // rows (u-8)*16..). Lane covers slot (prow=lane>>2, pchunk=lane&3) which
    // holds logical chunk (lane&3) ^ ((lane>>3)&3) of its row.
    const int    swz    = (((lane & 3) ^ ((lane >> 3) & 3)) << 3);  // ushorts
    const size_t srcrow = (size_t)(lane >> 2) * 512 + swz;
    const unsigned short* aGlob = zcat + (size_t)row0 * 512 + srcrow;
    const unsigned short* bGlob = ecat + (size_t)cbase0 * 512 + srcrow;

    // fragment-read swizzle: physical chunk = quad ^ ((m>>1)&3), kk-invariant
    const int xo = ((quad ^ ((m >> 1) & 3)) << 3);

    float    best_v[16];
    unsigned best_p[4];     // per i: 4 reg-slots x 8-bit candidate (nt*8+j)
#pragma unroll
    for (int r = 0; r < 16; ++r) best_v[r] = FLT_MAX;
#pragma unroll
    for (int i = 0; i < 4; ++i) best_p[i] = 0u;

    // prologue: stage global steps g=0 (buf0) and g=1 (buf1); esq for nt=0
    STAGE3(0, bGlob, 0, 0);
    STAGE3(BUF_U, bGlob, 32, 32);
    float es[8];
#pragma unroll
    for (int j = 0; j < 8; ++j) es[j] = esq[cbase0 + wcol + j * 16 + m];

    for (int nt = 0; nt < NT_TILES; ++nt) {
        const unsigned short* bNT  = bGlob + (size_t)nt * 131072;
        const unsigned short* bNT1 = bNT + 131072;
        floatx4 acc[4][8];
#pragma unroll
        for (int j = 0; j < 8; ++j) {
            const float e = es[j];
#pragma unroll
            for (int i = 0; i < 4; ++i) acc[i][j] = (floatx4){e, e, e, e};
        }

        int ob0 = 0, ob1 = BUF_U, ob2 = 2 * BUF_U;   // 24 % 3 == 0: aligns per nt
#pragma unroll 1
        for (int s = 0; s < STEPS_NT; ++s) {
            // counted drain: own stage(g) landed; stage(g+1) stays in flight.
            // only the very last step of the last nt needs a full drain.
            if (nt == NT_TILES - 1 && s == STEPS_NT - 1) {
                asm volatile("s_waitcnt vmcnt(0)" ::: "memory");
            } else {
                asm volatile("s_waitcnt vmcnt(6)" ::: "memory");
            }
            __builtin_amdgcn_s_barrier();
            __builtin_amdgcn_sched_barrier(0);
            const int s2 = s + 2;
            if (s2 < STEPS_NT) {
                const int k0n = s2 * 32;
                STAGE3(ob2, bNT, (k0n & 255) | ((k0n & 512) >> 1), k0n & 511);
            } else if (nt + 1 < NT_TILES) {
                const int k0n = (s2 - STEPS_NT) * 32;
                STAGE3(ob2, bNT1, (k0n & 255) | ((k0n & 512) >> 1), k0n & 511);
            }
            COMPUTE3(ob0);
            if (s == 20 && nt + 1 < NT_TILES) {      // esq prefetch for nt+1
#pragma unroll
                for (int j = 0; j < 8; ++j)
                    es[j] = esq[cbase0 + (nt + 1) * 256 + wcol + j * 16 + m];
            }
            const int tmp = ob0; ob0 = ob1; ob1 = ob2; ob2 = tmp;
        }
        // epilogue: acc IS the score. codes ascend in (nt,j): strict < =
        // first-min. Pure VALU: overlaps the in-flight next-nt stages.
#pragma unroll
        for (int j = 0; j < 8; ++j) {
            const unsigned cand = (unsigned)(nt * 8 + j);   // 7 bits
#pragma unroll
            for (int i = 0; i < 4; ++i)
#pragma unroll
                for (int reg = 0; reg < 4; ++reg) {
                    const float s = acc[i][j][reg];
                    const int r = i * 4 + reg;
                    if (s < best_v[r]) {
                        best_v[r] = s;
                        best_p[i] = (best_p[i] & ~(255u << (reg * 8))) | (cand << (reg * 8));
                    }
                }
        }
    }
    // reconstruct codes, butterfly across the 16 lanes sharing each row
    __syncthreads();               // staging LDS free for reuse (all drained)
    float* redv = (float*)&s_all[0];        // [128][2] floats (1 KB)
    int*   redi = (int*)&s_all[8192];       // [128][2] ints, disjoint region
#pragma unroll
    for (int i = 0; i < 4; ++i)
#pragma unroll
        for (int reg = 0; reg < 4; ++reg) {
            const int r = i * 4 + reg;
            const unsigned b = (best_p[i] >> (reg * 8)) & 255u;
            float v  = best_v[r];
            int   bi = cbase0 + (int)(b >> 3) * 256 + wcol + (int)(b & 7) * 16 + m;
#pragma unroll
            for (int off = 1; off < 16; off <<= 1) {
                const float ov = __shfl_xor(v, off, 64);
                const int   oi = __shfl_xor(bi, off, 64);
                if (ov < v || (ov == v && oi < bi)) { v = ov; bi = oi; }
            }
            if (m == 0) {
                const int row = wrow + i * 16 + quad * 4 + reg;
                redv[row * 2 + (w & 1)] = v;
                redi[row * 2 + (w & 1)] = bi;
            }
        }
    __syncthreads();
    if (t < 128) {
        const float v0 = redv[t * 2], v1 = redv[t * 2 + 1];
        const int   i0 = redi[t * 2], i1 = redi[t * 2 + 1];
        const bool  b1 = (v1 < v0) || (v1 == v0 && i1 < i0);
        const size_t o = (size_t)blockIdx.y * NROWS + blockIdx.x * 128 + t;
        part_v[o] = b1 ? v1 : v0;
        part_i[o] = b1 ? i1 : i0;
    }
}

#undef STAGE3
#undef COMPUTE3

// ---------------------------------------------------------------- merge partials + histogram
__global__ void k_reduce_part(const float* __restrict__ pv, const int* __restrict__ pi,
                              int* __restrict__ idx_i, float* __restrict__ idx_f,
                              int* __restrict__ counts) {
    const int r = blockIdx.x * blockDim.x + threadIdx.x;
    float v = pv[r]; int bi = pi[r];
#pragma unroll
    for (int c = 1; c < NCH; ++c) {
        const float v2 = pv[(size_t)c * NROWS + r];
        const int   i2 = pi[(size_t)c * NROWS + r];
        if (v2 < v || (v2 == v && i2 < bi)) { v = v2; bi = i2; }
    }
    idx_i[r] = bi;
    idx_f[r] = (float)bi;
    atomicAdd(&counts[bi], 1);
}

// ---------------------------------------------------------------- scan + new_cluster_size + n  (1 block, 1024 thr)
__global__ void k_scan_ncs(const int* __restrict__ counts, const float* __restrict__ ema_cs,
                           int* __restrict__ offsets, float* __restrict__ ncs_out,
                           float* __restrict__ ntot) {
    __shared__ int   wsum[16];
    __shared__ float red[16];
    const int t = threadIdx.x;
    const int lane = t & 63, w = t >> 6;
    int c[8]; int s = 0; float fs = 0.0f;
#pragma unroll
    for (int u = 0; u < 8; ++u) {
        c[u] = counts[t * 8 + u]; s += c[u];
        const float v = fmaf(0.99f, ema_cs[t * 8 + u], 0.01f * (float)c[u]);
        ncs_out[t * 8 + u] = v;
        fs += v;
    }
    int inc = s;
#pragma unroll
    for (int off = 1; off < 64; off <<= 1) {
        const int n = __shfl_up(inc, off, 64);
        if (lane >= off) inc += n;
    }
#pragma unroll
    for (int off = 32; off > 0; off >>= 1) fs += __shfl_down(fs, off, 64);
    if (lane == 63) wsum[w] = inc;
    if (lane == 0)  red[w]  = fs;
    __syncthreads();
    if (t < 16) {
        int v = wsum[t];
#pragma unroll
        for (int off = 1; off < 16; off <<= 1) {
            const int n = __shfl_up(v, off, 64);
            if (t >= off) v += n;
        }
        wsum[t] = v;
        float fv = red[t];
#pragma unroll
        for (int off = 8; off > 0; off >>= 1) fv += __shfl_down(fv, off, 16);
        if (t == 0) *ntot = fv;
    }
    __syncthreads();
    int base = (w > 0 ? wsum[w - 1] : 0) + (inc - s);
#pragma unroll
    for (int u = 0; u < 8; ++u) { offsets[t * 8 + u] = base; base += c[u]; }
}

// ---------------------------------------------------------------- zq + loss partials + bucket scatter
__global__ void k_zq(const float* __restrict__ z, const float* __restrict__ emb,
                     const int* __restrict__ idx_i, const int* __restrict__ offsets,
                     int* __restrict__ cursor, int* __restrict__ buckets,
                     float* __restrict__ zq, float* __restrict__ losspart) {
    __shared__ float lred[4];
    const int t = threadIdx.x;
    const int wr = t >> 6, lane = t & 63;
    const int row = blockIdx.x * 4 + wr;
    const int code = idx_i[row];
    float4 zv = ((const float4*)z)[row * 64 + lane];
    float4 ev = ((const float4*)emb)[(size_t)code * 64 + lane];
    float4 o = make_float4(zv.x + (ev.x - zv.x), zv.y + (ev.y - zv.y),
                           zv.z + (ev.z - zv.z), zv.w + (ev.w - zv.w));
    ((float4*)zq)[row * 64 + lane] = o;
    float dx = ev.x - zv.x, dy = ev.y - zv.y, dz = ev.z - zv.z, dw = ev.w - zv.w;
    float s = fmaf(dx, dx, fmaf(dy, dy, fmaf(dz, dz, dw * dw)));
#pragma unroll
    for (int off = 32; off > 0; off >>= 1) s += __shfl_down(s, off, 64);
    if (lane == 0) {
        lred[wr] = s;
        const int pos = atomicAdd(&cursor[code], 1);
        buckets[offsets[code] + pos] = row;
    }
    __syncthreads();
    if (t == 0) losspart[blockIdx.x] = (lred[0] + lred[1]) + (lred[2] + lred[3]);
}

// ---------------------------------------------------------------- dw + new_ema_w + new_embedding (+loss tail block)
__global__ void k_dw_nemb(const float* __restrict__ z, const float* __restrict__ ema_w,
                          const int* __restrict__ counts, const int* __restrict__ offsets,
                          const int* __restrict__ buckets, const float* __restrict__ ncs,
                          const float* __restrict__ ntot_p, const float* __restrict__ losspart,
                          float* __restrict__ nemaw, float* __restrict__ nemb,
                          float* __restrict__ loss_out) {
    __shared__ float lred[4];
    if (blockIdx.x == K_CODES) {          // loss finalize
        const int t = threadIdx.x;        // 256
        float s = 0.0f;
        for (int i = t; i < 8192; i += 256) s += losspart[i];
#pragma unroll
        for (int off = 32; off > 0; off >>= 1) s += __shfl_down(s, off, 64);
        if ((t & 63) == 0) lred[t >> 6] = s;
        __syncthreads();
        if (t == 0)
            *loss_out = 0.25f * ((lred[0] + lred[1]) + (lred[2] + lred[3])) / 8388608.0f;
        return;
    }
    const int code = blockIdx.x;
    const int d    = threadIdx.x;         // 256 = DIM
    const int cnt  = counts[code];
    const int off  = offsets[code];
    float acc = 0.0f;
    for (int it = 0; it < cnt; ++it)
        acc += z[(size_t)buckets[off + it] * DIM + d];
    const float wv = fmaf(0.99f, ema_w[(size_t)code * DIM + d], 0.01f * acc);
    nemaw[(size_t)code * DIM + d] = wv;
    const float n  = *ntot_p;
    const float cs = (ncs[code] + 1e-5f) * (n / (n + (float)K_CODES * 1e-5f));
    nemb[(size_t)code * DIM + d] = wv / cs;
}

// ================================================================ fp32 fallback path (round-1 verified)
#define BM   64
#define BN   128
#define LSTR 36

__global__ void k_esq_zero_fb(const float* __restrict__ emb, float* __restrict__ esq,
                              float* __restrict__ zbuf) {
    const int gid  = blockIdx.x * blockDim.x + threadIdx.x;
    if (gid < K_CODES + 2) zbuf[gid] = 0.0f;
    const int code = gid >> 6;
    const int lane = gid & 63;
    float4 v = ((const float4*)emb)[code * 64 + lane];
    float s = fmaf(v.x, v.x, fmaf(v.y, v.y, fmaf(v.z, v.z, v.w * v.w)));
#pragma unroll
    for (int off = 32; off > 0; off >>= 1) s += __shfl_down(s, off, 64);
    if (lane == 0) esq[code] = s;
}

__global__ void k_init_nemaw_fb(const float* __restrict__ ema_w, float* __restrict__ out) {
    const int i = blockIdx.x * blockDim.x + threadIdx.x;
    float4 v = ((const float4*)ema_w)[i];
    ((float4*)out)[i] = make_float4(0.99f * v.x, 0.99f * v.y, 0.99f * v.z, 0.99f * v.w);
}

__global__ __launch_bounds__(256, 2) void k_argmin_fb(
        const float* __restrict__ z, const float* __restrict__ emb,
        const float* __restrict__ esq, int* __restrict__ idx_i, float* __restrict__ idx_f) {
    __shared__ float z_s[BM * LSTR];
    __shared__ float e_s[BN * LSTR];
    const int t = threadIdx.x, tx = t & 15, ty = t >> 4;
    const int row0 = blockIdx.x * BM;
    float best[4]; int bidx[4];
#pragma unroll
    for (int r = 0; r < 4; ++r) { best[r] = FLT_MAX; bidx[r] = 0; }
    for (int k0 = 0; k0 < K_CODES; k0 += BN) {
        float acc[4][8];
#pragma unroll
        for (int r = 0; r < 4; ++r)
#pragma unroll
            for (int c = 0; c < 8; ++c) acc[r][c] = 0.0f;
        for (int d0 = 0; d0 < DIM; d0 += 32) {
            __syncthreads();
#pragma unroll
            for (int i = 0; i < 2; ++i) {
                int f = i * 256 + t, r = f >> 3, c4 = (f & 7) << 2;
                *(float4*)&z_s[r * LSTR + c4] =
                    *(const float4*)(z + (size_t)(row0 + r) * DIM + d0 + c4);
            }
#pragma unroll
            for (int i = 0; i < 4; ++i) {
                int f = i * 256 + t, c = f >> 3, c4 = (f & 7) << 2;
                *(float4*)&e_s[c * LSTR + c4] =
                    *(const float4*)(emb + (size_t)(k0 + c) * DIM + d0 + c4);
            }
            __syncthreads();
#pragma unroll
            for (int dd = 0; dd < 32; dd += 4) {
                float4 a[4], b[8];
#pragma unroll
                for (int j = 0; j < 4; ++j)
                    a[j] = *(const float4*)&z_s[(ty * 4 + j) * LSTR + dd];
#pragma unroll
                for (int j = 0; j < 8; ++j)
                    b[j] = *(const float4*)&e_s[(tx + 16 * j) * LSTR + dd];
#pragma unroll
                for (int r = 0; r < 4; ++r)
#pragma unroll
                    for (int c = 0; c < 8; ++c) {
                        acc[r][c] = fmaf(a[r].x, b[c].x, acc[r][c]);
                        acc[r][c] = fmaf(a[r].y, b[c].y, acc[r][c]);
                        acc[r][c] = fmaf(a[r].z, b[c].z, acc[r][c]);
                        acc[r][c] = fmaf(a[r].w, b[c].w, acc[r][c]);
                    }
            }
        }
#pragma unroll
        for (int c = 0; c < 8; ++c) {
            const int code = k0 + tx + 16 * c;
            const float es = esq[code];
#pragma unroll
            for (int r = 0; r < 4; ++r) {
                float s = fmaf(-2.0f, acc[r][c], es);
                if (s < best[r] || (s == best[r] && code < bidx[r])) {
                    best[r] = s; bidx[r] = code;
                }
            }
        }
    }
    __syncthreads();
    float* rv = e_s; int* ri = (int*)z_s;
#pragma unroll
    for (int r = 0; r < 4; ++r) {
        rv[(ty * 4 + r) * 16 + tx] = best[r];
        ri[(ty * 4 + r) * 16 + tx] = bidx[r];
    }
    __syncthreads();
    if (t < 64) {
        float mv = rv[t * 16]; int mi = ri[t * 16];
#pragma unroll
        for (int i = 1; i < 16; ++i) {
            float v = rv[t * 16 + i]; int vi = ri[t * 16 + i];
            if (v < mv || (v == mv && vi < mi)) { mv = v; mi = vi; }
        }
        idx_i[row0 + t] = mi;
        idx_f[row0 + t] = (float)mi;
    }
}

__global__ void k_gather_fb(const float* __restrict__ z, const float* __restrict__ emb,
                            const int* __restrict__ idx_i, float* __restrict__ zq,
                            float* __restrict__ nemaw, float* __restrict__ counts,
                            float* __restrict__ loss) {
    const int gid  = blockIdx.x * blockDim.x + threadIdx.x;
    const int row  = gid >> 6;
    const int lane = gid & 63;
    const int code = idx_i[row];
    float4 zv = ((const float4*)z)[row * 64 + lane];
    float4 ev = ((const float4*)emb)[(size_t)code * 64 + lane];
    float4 o = make_float4(zv.x + (ev.x - zv.x), zv.y + (ev.y - zv.y),
                           zv.z + (ev.z - zv.z), zv.w + (ev.w - zv.w));
    ((float4*)zq)[row * 64 + lane] = o;
    float dx = ev.x - zv.x, dy = ev.y - zv.y, dz = ev.z - zv.z, dw = ev.w - zv.w;
    float s = fmaf(dx, dx, fmaf(dy, dy, fmaf(dz, dz, dw * dw)));
#pragma unroll
    for (int off = 32; off > 0; off >>= 1) s += __shfl_down(s, off, 64);
    if (lane == 0) { atomicAdd(loss, s); atomicAdd(&counts[code], 1.0f); }
    float* base = nemaw + (size_t)code * DIM + lane * 4;
    atomicAdd(base + 0, 0.01f * zv.x);
    atomicAdd(base + 1, 0.01f * zv.y);
    atomicAdd(base + 2, 0.01f * zv.z);
    atomicAdd(base + 3, 0.01f * zv.w);
}

__global__ void k_ncs_fb(const float* __restrict__ ema_cs, const float* __restrict__ counts,
                         float* __restrict__ ncs_out, float* __restrict__ ntot,
                         const float* __restrict__ loss_in, float* __restrict__ loss_out) {
    __shared__ float red[16];
    const int t = threadIdx.x;
    float s = 0.0f;
    for (int i = t; i < K_CODES; i += 1024) {
        float v = fmaf(0.99f, ema_cs[i], 0.01f * counts[i]);
        ncs_out[i] = v; s += v;
    }
#pragma unroll
    for (int off = 32; off > 0; off >>= 1) s += __shfl_down(s, off, 64);
    if ((t & 63) == 0) red[t >> 6] = s;
    __syncthreads();
    if (t < 16) {
        float v = red[t];
#pragma unroll
        for (int off = 8; off > 0; off >>= 1) v += __shfl_down(v, off, 16);
        if (t == 0) { *ntot = v; *loss_out = 0.25f * (*loss_in) / 8388608.0f; }
    }
}

__global__ void k_nemb_fb(const float* __restrict__ nemaw, const float* __restrict__ ncs,
                          const float* __restrict__ ntot_p, float* __restrict__ nemb) {
    const int i4 = blockIdx.x * blockDim.x + threadIdx.x;
    const int k  = i4 >> 6;
    const float n   = *ntot_p;
    const float inv = n / (n + (float)K_CODES * 1e-5f);
    const float cs  = (ncs[k] + 1e-5f) * inv;
    float4 wv = ((const float4*)nemaw)[i4];
    ((float4*)nemb)[i4] = make_float4(wv.x / cs, wv.y / cs, wv.z / cs, wv.w / cs);
}

extern "C" void kernel_launch(void* const* d_in, const int* in_sizes, int n_in,
                              void* d_out, int out_size, void* d_ws, size_t ws_size,
                              hipStream_t stream) {
    const float* z      = (const float*)d_in[0];
    const float* emb    = (const float*)d_in[1];
    const float* ema_cs = (const float*)d_in[2];
    const float* ema_w  = (const float*)d_in[3];
    float* out = (float*)d_out;
    char* wsb = (char*)d_ws;

    // ---- MFMA-path workspace layout (bytes), total 43,417,616 (NCH=2 uses
    // only half of part_v/part_i but offsets kept from r3 layout)
    unsigned short* zcat    = (unsigned short*)wsb;                  // 33,554,432
    unsigned short* ecat    = (unsigned short*)(wsb + 33554432);     //  8,388,608
    float*          part_v  = (float*)(wsb + 41943040);              //    524,288
    int*            part_i  = (int*)  (wsb + 42467328);              //    524,288
    float*          esq     = (float*)(wsb + 42991616);              //     32,768
    int*            ws_idx  = (int*)  (wsb + 43024384);              //    131,072
    int*            counts  = (int*)  (wsb + 43155456);              //     32,768
    int*            cursor  = (int*)  (wsb + 43188224);              //     32,768 (contiguous w/ counts)
    int*            offsets = (int*)  (wsb + 43220992);              //     32,768
    int*            buckets = (int*)  (wsb + 43253760);              //    131,072
    float*          lpart   = (float*)(wsb + 43384832);              //     32,768
    float*          ws_loss = (float*)(wsb + 43417600);
    float*          ws_ntot = ws_loss + 1;

    if (ws_size >= (size_t)43417616) {
        // one-time opt-in for 72 KB dynamic LDS (default cap is 64 KB).
        // host-side attribute set, not stream-ordered: graph-capture safe.
        static bool lds_attr_set = false;
        if (!lds_attr_set) {
            (void)hipFuncSetAttribute((const void*)k_argmin_mfma,
                                      hipFuncAttributeMaxDynamicSharedMemorySize,
                                      LDS_BYTES);
            lds_attr_set = true;
        }
        k_prep       <<<10240, 256, 0, stream>>>(z, emb, zcat, ecat, esq, counts);
        k_argmin_mfma<<<dim3(NROWS / 128, NCH), 256, LDS_BYTES, stream>>>(
            zcat, ecat, esq, part_v, part_i);
        k_reduce_part<<<NROWS / 256, 256, 0, stream>>>(part_v, part_i, ws_idx,
                                                       out + O_IDX, counts);
        k_scan_ncs   <<<1, 1024, 0, stream>>>(counts, ema_cs, offsets,
                                              out + O_NCS, ws_ntot);
        k_zq         <<<NROWS / 4, 256, 0, stream>>>(z, emb, ws_idx, offsets, cursor,
                                                     buckets, out + O_ZQ, lpart);
        k_dw_nemb    <<<K_CODES + 1, 256, 0, stream>>>(z, ema_w, counts, offsets, buckets,
                                                       out + O_NCS, ws_ntot, lpart,
                                                       out + O_NEMAW, out + O_NEMB,
                                                       out + O_LOSS);
    } else {
        // small-ws fallback (round-1 verified fp32 path)
        int*   f_idx    = (int*)wsb;
        float* f_counts = (float*)(wsb + 131072);
        float* f_loss   = f_counts + K_CODES;
        float* f_ntot   = f_loss + 1;
        float* f_esq    = (float*)(wsb + 163856);
        k_esq_zero_fb  <<<2048, 256, 0, stream>>>(emb, f_esq, f_counts);
        k_init_nemaw_fb<<<2048, 256, 0, stream>>>(ema_w, out + O_NEMAW);
        k_argmin_fb    <<<NROWS / BM, 256, 0, stream>>>(z, emb, f_esq, f_idx, out + O_IDX);
        k_gather_fb    <<<NROWS / 4, 256, 0, stream>>>(z, emb, f_idx, out + O_ZQ,
                                                       out + O_NEMAW, f_counts, f_loss);
        k_ncs_fb       <<<1, 1024, 0, stream>>>(ema_cs, f_counts, out + O_NCS, f_ntot,
                                                f_loss, out + O_LOSS);
        k_nemb_fb      <<<2048, 256, 0, stream>>>(out + O_NEMAW, out + O_NCS, f_ntot,
                                                  out + O_NEMB);
    }
}

// Round 6
// 655.554 us; speedup vs baseline: 1.0435x; 1.0435x over previous
//
#include <hip/hip_runtime.h>
#include <cfloat>

// VQ-VAE vector quantizer. Round 11: 8-phase-style port of the argmin GEMM.
// r5-r10 pinned the 4-wave/128x256 structure at 43-46% MfmaUtil; r10's null
// traced to (a) depth-1 landing window, (b) compiler-inserted vmcnt before
// C++ ds_reads (alias with global_load_lds). Fix per guide T3/T4 + rule #18:
// 512 thr / 8 waves, 256x256 tile, BK=32, 4-KT ring buffer (128 KB dynamic
// LDS), inline-asm ds_read_b128 (hidden from alias analysis), per-phase
// lgkmcnt(0)+sched_barrier(0), per-KT entry vmcnt(8) (stage leads by 3 KTs
// -> ~6-phase landing window), setprio(1) around MFMA clusters.
// N=32768 rows, K=8192 codes, D=256.
#define K_CODES 8192
#define DIM     256
#define NROWS   32768

// d_out float offsets (outputs concatenated in reference return order)
#define O_ZQ    0
#define O_LOSS  8388608
#define O_IDX   8388609
#define O_NEMB  8421377
#define O_NCS   10518529
#define O_NEMAW 10526721

// ---- MFMA path params
#define NCH          2                    // code chunks
#define CODES_PER_CH (K_CODES / NCH)      // 4096
#define NT_TILES     (CODES_PER_CH / 256) // 16
#define KT_PER_NT    24                   // virtual K 768 / BK 32
#define KT_TOTAL     (NT_TILES * KT_PER_NT) // 384
#define LDS_BYTES    131072               // 4 ring buffers x 32 KB

typedef __attribute__((ext_vector_type(8))) short short8;
typedef __attribute__((ext_vector_type(4))) float floatx4;

__device__ __forceinline__ unsigned short f2bf_rne(float x) {
    unsigned u = __float_as_uint(x);
    u += 0x7fffu + ((u >> 16) & 1u);
    return (unsigned short)(u >> 16);
}
__device__ __forceinline__ float bf2f(unsigned short h) {
    return __uint_as_float(((unsigned)h) << 16);
}
__device__ __forceinline__ void async16(const void* g, void* l) {
    __builtin_amdgcn_global_load_lds(
        (const __attribute__((address_space(1))) void*)g,
        (__attribute__((address_space(3))) void*)l, 16, 0, 0);
}
__device__ __forceinline__ unsigned ldsaddr(const void* p) {
    return (unsigned)(unsigned long long)
        (const __attribute__((address_space(3))) void*)p;
}
// inline-asm LDS read: invisible to alias analysis (no auto vmcnt/lgkm
// insertion); MUST be followed by lgkmcnt(0)+sched_barrier(0) before use.
#define DSR(dst, addr, off)                                                     \
    asm volatile("ds_read_b128 %0, %1 offset:" #off : "=v"(dst) : "v"(addr))

// ---------------------------------------------------------------- fused convert: z & emb -> {hi,lo} bf16 + |e|^2 + zero
__global__ void k_prep(const float* __restrict__ z, const float* __restrict__ emb,
                       unsigned short* __restrict__ zcat, unsigned short* __restrict__ ecat,
                       float* __restrict__ esq, int* __restrict__ zero16k) {
    const int b = blockIdx.x;
    if (b < 8192) {
        const int i = b * 256 + threadIdx.x;         // float4 idx, 2,097,152
        const int row = i >> 6;
        const int col = (i & 63) << 2;
        float4 v = ((const float4*)z)[i];
        // fold -2 into z: bf16(-2z) == -2*bf16(z) exactly (pow2 scale)
        float nx = -2.0f * v.x, ny = -2.0f * v.y, nz = -2.0f * v.z, nw = -2.0f * v.w;
        ushort4 h, l;
        h.x = f2bf_rne(nx); l.x = f2bf_rne(nx - bf2f(h.x));
        h.y = f2bf_rne(ny); l.y = f2bf_rne(ny - bf2f(h.y));
        h.z = f2bf_rne(nz); l.z = f2bf_rne(nz - bf2f(h.z));
        h.w = f2bf_rne(nw); l.w = f2bf_rne(nw - bf2f(h.w));
        *(ushort4*)&zcat[(size_t)row * 512 + col]       = h;
        *(ushort4*)&zcat[(size_t)row * 512 + 256 + col] = l;
    } else {
        const int gid  = (b - 8192) * 256 + threadIdx.x;  // 0..524287
        if (gid < 2 * K_CODES) zero16k[gid] = 0;          // counts + cursor
        const int code = gid >> 6;
        const int lane = gid & 63;
        const int col  = lane << 2;
        float4 v = ((const float4*)emb)[code * 64 + lane];
        ushort4 h, l;
        h.x = f2bf_rne(v.x); l.x = f2bf_rne(v.x - bf2f(h.x));
        h.y = f2bf_rne(v.y); l.y = f2bf_rne(v.y - bf2f(h.y));
        h.z = f2bf_rne(v.z); l.z = f2bf_rne(v.z - bf2f(h.z));
        h.w = f2bf_rne(v.w); l.w = f2bf_rne(v.w - bf2f(h.w));
        *(ushort4*)&ecat[(size_t)code * 512 + col]       = h;
        *(ushort4*)&ecat[(size_t)code * 512 + 256 + col] = l;
        float s = fmaf(v.x, v.x, fmaf(v.y, v.y, fmaf(v.z, v.z, v.w * v.w)));
#pragma unroll
        for (int off = 32; off > 0; off >>= 1) s += __shfl_down(s, off, 64);
        if (lane == 0) esq[code] = s;
    }
}

// ---------------------------------------------------------------- MFMA argmin GEMM (virtual K=768, BK=32, 256x256 tile)
// score(n,k) = esq[k] + dot(zcat_n, ecat_k segs), zcat encodes -2z.
// A segs {hi,hi,lo}: off_a=(k0&255)|((k0&512)>>1); B segs {hi,lo,hi}: off_b=k0&511.
// 8 waves (2M x 4N); wave tile 128x64; acc 8x4 of 16x16x32 (128 AGPRs).
// KT = one BK=32 K-tile; 24 KT per code-tile (nt), 384 total. Ring of 4 LDS
// buffers, KT g in buf g&3; during KT g stage KT g+3 (A-half phase 0, B-half
// phase 1) -> landing window ~6 phases. Per-KT entry: vmcnt(8) (= stages of
// g+1,g+2 stay in flight) + s_barrier. Per phase: asm ds_read fragments,
// issue stage, lgkmcnt(0)+sched_barrier(0), setprio(1), 16 MFMA, setprio(0).
// LDS layout per buffer: A 256 rows x 64 B (16 KB) then B 256 x 64 B; row =
// 4 x 16B chunks; logical chunk c of row R at physical c ^ ((R>>1)&3)
// (conflict-free, verified r6-r10: 0 conflicts). Stage pre-swizzles the
// GLOBAL source (linear LDS dest per global_load_lds).
__global__ __launch_bounds__(512, 2) void k_argmin_mfma(
        const unsigned short* __restrict__ zcat, const unsigned short* __restrict__ ecat,
        const float* __restrict__ esq,
        float* __restrict__ part_v, int* __restrict__ part_i) {
    extern __shared__ __align__(16) unsigned short s_all[];
    const int t    = threadIdx.x;        // 0..511
    const int w    = t >> 6;             // 0..7
    const int lane = t & 63;
    const int quad = lane >> 4;
    const int m    = lane & 15;
    const int wr   = w >> 2;             // 0..1  (row half)
    const int wc   = w & 3;              // 0..3  (code quarter)
    const int row0   = blockIdx.x * 256;
    const int cbase0 = blockIdx.y * CODES_PER_CH;

    // staging geometry: per KT, A = 1024 16B slots (256 rows x 4 chunks),
    // B same. 512 threads x 2 loads each per half (q=1 is +128 rows: same
    // chunk and same swizzle since 128 rows == 0 mod the (R>>1)&3 key).
    const int prow = t >> 2;             // 0..127
    const int pch  = t & 3;
    const int lc   = pch ^ ((prow >> 1) & 3);
    const unsigned short* aSrc = zcat + (size_t)(row0 + prow) * 512 + lc * 8;
    const unsigned short* bSrc = ecat + (size_t)(cbase0 + prow) * 512 + lc * 8;
    const int dstU = prow * 32 + pch * 8;   // ushort offset within region

    // fragment-read addresses (bytes): row stride 64 B, chunk swizzle
    // physical chunk = quad ^ ((m>>1)&3) (kk-invariant, matches staging key)
    const int xo2 = (quad ^ ((m >> 1) & 3)) << 4;
    const unsigned lb = ldsaddr(s_all);
    const unsigned aRdTB = lb + (unsigned)((wr * 128 + m) * 64 + xo2);
    const unsigned bRdTB = lb + 16384u + (unsigned)((wc * 64 + m) * 64 + xo2);

    float    best_v[32];
    unsigned best_p[8];     // per i: 4 reg-slots x 8-bit candidate (nt*4+j)
#pragma unroll
    for (int r = 0; r < 32; ++r) best_v[r] = FLT_MAX;
#pragma unroll
    for (int i = 0; i < 8; ++i) best_p[i] = 0u;

    // prologue: stage KT 0,1,2 into ring bufs 0,1,2; es for nt=0
#pragma unroll
    for (int G = 0; G < 3; ++G) {
        const int k0   = G * 32;
        const int offA = (k0 & 255) | ((k0 & 512) >> 1);
        const int offB = k0 & 511;
        unsigned short* dA = s_all + G * 16384 + dstU;
        async16(aSrc + offA, dA);
        async16(aSrc + 65536 + offA, dA + 4096);
        async16(bSrc + offB, dA + 8192);
        async16(bSrc + 65536 + offB, dA + 12288);
    }
    float es[4];
#pragma unroll
    for (int j = 0; j < 4; ++j) es[j] = esq[cbase0 + wc * 64 + j * 16 + m];

    for (int nt = 0; nt < NT_TILES; ++nt) {
        floatx4 acc[8][4];
#pragma unroll
        for (int j = 0; j < 4; ++j) {
            const float e = es[j];
#pragma unroll
            for (int i = 0; i < 8; ++i) acc[i][j] = (floatx4){e, e, e, e};
        }

#pragma unroll 1
        for (int kk = 0; kk < KT_PER_NT; ++kk) {
            const int g = nt * KT_PER_NT + kk;
            // entry checkpoint: all KT-g loads landed; stages of g+1,g+2
            // (8 loads) stay in flight across the barrier. Never 0 in
            // steady state; drains only at the tail.
            if (g < KT_TOTAL - 2)
                asm volatile("s_waitcnt vmcnt(8)" ::: "memory");
            else if (g == KT_TOTAL - 2)
                asm volatile("s_waitcnt vmcnt(4)" ::: "memory");
            else
                asm volatile("s_waitcnt vmcnt(0)" ::: "memory");
            __builtin_amdgcn_s_barrier();

            // staging setup for KT g+3 (overwrites buf (g-1)&3, whose last
            // readers all passed the entry barrier above)
            const int G = g + 3;
            const unsigned short* sA = aSrc;
            const unsigned short* sB = bSrc;
            unsigned short* dD = s_all;
            if (G < KT_TOTAL) {
                const int ntS = G / KT_PER_NT;
                const int k0  = (G - ntS * KT_PER_NT) * 32;
                sA = aSrc + ((k0 & 255) | ((k0 & 512) >> 1));
                sB = bSrc + (size_t)ntS * 131072 + (k0 & 511);
                dD = s_all + (G & 3) * 16384 + dstU;
            }
            const unsigned bub   = (unsigned)((g & 3) << 15);
            const unsigned addrA = aRdTB + bub;
            const unsigned addrB = bRdTB + bub;

            short8 af[4], bf[4];
            // ---- phase 0: read B j0-3 + A i0-3; stage A-half of g+3
            DSR(bf[0], addrB, 0);    DSR(bf[1], addrB, 1024);
            DSR(bf[2], addrB, 2048); DSR(bf[3], addrB, 3072);
            DSR(af[0], addrA, 0);    DSR(af[1], addrA, 1024);
            DSR(af[2], addrA, 2048); DSR(af[3], addrA, 3072);
            if (G < KT_TOTAL) {
                async16(sA, dD);
                async16(sA + 65536, dD + 4096);
            }
            asm volatile("s_waitcnt lgkmcnt(0)" ::: "memory");
            __builtin_amdgcn_sched_barrier(0);
            __builtin_amdgcn_s_setprio(1);
#pragma unroll
            for (int i = 0; i < 4; ++i)
#pragma unroll
                for (int j = 0; j < 4; ++j)
                    acc[i][j] = __builtin_amdgcn_mfma_f32_16x16x32_bf16(
                        af[i], bf[j], acc[i][j], 0, 0, 0);
            __builtin_amdgcn_s_setprio(0);
            __builtin_amdgcn_s_barrier();
            // ---- phase 1: read A i4-7 (bf reused); stage B-half of g+3
            DSR(af[0], addrA, 4096); DSR(af[1], addrA, 5120);
            DSR(af[2], addrA, 6144); DSR(af[3], addrA, 7168);
            if (G < KT_TOTAL) {
                async16(sB, dD + 8192);
                async16(sB + 65536, dD + 12288);
            }
            asm volatile("s_waitcnt lgkmcnt(0)" ::: "memory");
            __builtin_amdgcn_sched_barrier(0);
            __builtin_amdgcn_s_setprio(1);
#pragma unroll
            for (int i = 0; i < 4; ++i)
#pragma unroll
                for (int j = 0; j < 4; ++j)
                    acc[4 + i][j] = __builtin_amdgcn_mfma_f32_16x16x32_bf16(
                        af[i], bf[j], acc[4 + i][j], 0, 0, 0);
            __builtin_amdgcn_s_setprio(0);
        }
        // epilogue: acc IS the score. codes ascend in (nt,j): strict < =
        // first-min. Register-only; in-flight stages keep streaming.
#pragma unroll
        for (int j = 0; j < 4; ++j) {
            const unsigned cand = (unsigned)(nt * 4 + j);   // 6 bits
#pragma unroll
            for (int i = 0; i < 8; ++i)
#pragma unroll
                for (int reg = 0; reg < 4; ++reg) {
                    const float s = acc[i][j][reg];
                    const int r = i * 4 + reg;
                    if (s < best_v[r]) {
                        best_v[r] = s;
                        best_p[i] = (best_p[i] & ~(255u << (reg * 8))) | (cand << (reg * 8));
                    }
                }
        }
        if (nt + 1 < NT_TILES) {    // es prefetch for next code tile
#pragma unroll
            for (int j = 0; j < 4; ++j)
                es[j] = esq[cbase0 + (nt + 1) * 256 + wc * 64 + j * 16 + m];
        }
    }
    // reconstruct codes, butterfly across the 16 lanes sharing each row
    __syncthreads();               // all staging drained (last KT waited vmcnt 0)
    float* redv = (float*)s_all;            // [256][4] floats (4 KB)
    int*   redi = (int*)(s_all + 2048);     // [256][4] ints, disjoint (4 KB)
#pragma unroll
    for (int i = 0; i < 8; ++i)
#pragma unroll
        for (int reg = 0; reg < 4; ++reg) {
            const int r = i * 4 + reg;
            const unsigned b = (best_p[i] >> (reg * 8)) & 255u;
            float v  = best_v[r];
            int   bi = cbase0 + (int)(b >> 2) * 256 + wc * 64 + (int)(b & 3) * 16 + m;
#pragma unroll
            for (int off = 1; off < 16; off <<= 1) {
                const float ov = __shfl_xor(v, off, 64);
                const int   oi = __shfl_xor(bi, off, 64);
                if (ov < v || (ov == v && oi < bi)) { v = ov; bi = oi; }
            }
            if (m == 0) {
                const int rl = wr * 128 + i * 16 + quad * 4 + reg;
                redv[rl * 4 + wc] = v;
                redi[rl * 4 + wc] = bi;
            }
        }
    __syncthreads();
    if (t < 256) {
        float v = redv[t * 4]; int bi = redi[t * 4];
#pragma unroll
        for (int c = 1; c < 4; ++c) {
            const float v2 = redv[t * 4 + c];
            const int   i2 = redi[t * 4 + c];
            if (v2 < v || (v2 == v && i2 < bi)) { v = v2; bi = i2; }
        }
        const size_t o = (size_t)blockIdx.y * NROWS + blockIdx.x * 256 + t;
        part_v[o] = v;
        part_i[o] = bi;
    }
}

// ---------------------------------------------------------------- merge partials + histogram
__global__ void k_reduce_part(const float* __restrict__ pv, const int* __restrict__ pi,
                              int* __restrict__ idx_i, float* __restrict__ idx_f,
                              int* __restrict__ counts) {
    const int r = blockIdx.x * blockDim.x + threadIdx.x;
    float v = pv[r]; int bi = pi[r];
#pragma unroll
    for (int c = 1; c < NCH; ++c) {
        const float v2 = pv[(size_t)c * NROWS + r];
        const int   i2 = pi[(size_t)c * NROWS + r];
        if (v2 < v || (v2 == v && i2 < bi)) { v = v2; bi = i2; }
    }
    idx_i[r] = bi;
    idx_f[r] = (float)bi;
    atomicAdd(&counts[bi], 1);
}

// ---------------------------------------------------------------- scan + new_cluster_size + n  (1 block, 1024 thr)
__global__ void k_scan_ncs(const int* __restrict__ counts, const float* __restrict__ ema_cs,
                           int* __restrict__ offsets, float* __restrict__ ncs_out,
                           float* __restrict__ ntot) {
    __shared__ int   wsum[16];
    __shared__ float red[16];
    const int t = threadIdx.x;
    const int lane = t & 63, w = t >> 6;
    int c[8]; int s = 0; float fs = 0.0f;
#pragma unroll
    for (int u = 0; u < 8; ++u) {
        c[u] = counts[t * 8 + u]; s += c[u];
        const float v = fmaf(0.99f, ema_cs[t * 8 + u], 0.01f * (float)c[u]);
        ncs_out[t * 8 + u] = v;
        fs += v;
    }
    int inc = s;
#pragma unroll
    for (int off = 1; off < 64; off <<= 1) {
        const int n = __shfl_up(inc, off, 64);
        if (lane >= off) inc += n;
    }
#pragma unroll
    for (int off = 32; off > 0; off >>= 1) fs += __shfl_down(fs, off, 64);
    if (lane == 63) wsum[w] = inc;
    if (lane == 0)  red[w]  = fs;
    __syncthreads();
    if (t < 16) {
        int v = wsum[t];
#pragma unroll
        for (int off = 1; off < 16; off <<= 1) {
            const int n = __shfl_up(v, off, 64);
            if (t >= off) v += n;
        }
        wsum[t] = v;
        float fv = red[t];
#pragma unroll
        for (int off = 8; off > 0; off >>= 1) fv += __shfl_down(fv, off, 16);
        if (t == 0) *ntot = fv;
    }
    __syncthreads();
    int base = (w > 0 ? wsum[w - 1] : 0) + (inc - s);
#pragma unroll
    for (int u = 0; u < 8; ++u) { offsets[t * 8 + u] = base; base += c[u]; }
}

// ---------------------------------------------------------------- zq + loss partials + bucket scatter
__global__ void k_zq(const float* __restrict__ z, const float* __restrict__ emb,
                     const int* __restrict__ idx_i, const int* __restrict__ offsets,
                     int* __restrict__ cursor, int* __restrict__ buckets,
                     float* __restrict__ zq, float* __restrict__ losspart) {
    __shared__ float lred[4];
    const int t = threadIdx.x;
    const int wr = t >> 6, lane = t & 63;
    const int row = blockIdx.x * 4 + wr;
    const int code = idx_i[row];
    float4 zv = ((const float4*)z)[row * 64 + lane];
    float4 ev = ((const float4*)emb)[(size_t)code * 64 + lane];
    float4 o = make_float4(zv.x + (ev.x - zv.x), zv.y + (ev.y - zv.y),
                           zv.z + (ev.z - zv.z), zv.w + (ev.w - zv.w));
    ((float4*)zq)[row * 64 + lane] = o;
    float dx = ev.x - zv.x, dy = ev.y - zv.y, dz = ev.z - zv.z, dw = ev.w - zv.w;
    float s = fmaf(dx, dx, fmaf(dy, dy, fmaf(dz, dz, dw * dw)));
#pragma unroll
    for (int off = 32; off > 0; off >>= 1) s += __shfl_down(s, off, 64);
    if (lane == 0) {
        lred[wr] = s;
        const int pos = atomicAdd(&cursor[code], 1);
        buckets[offsets[code] + pos] = row;
    }
    __syncthreads();
    if (t == 0) losspart[blockIdx.x] = (lred[0] + lred[1]) + (lred[2] + lred[3]);
}

// ---------------------------------------------------------------- dw + new_ema_w + new_embedding (+loss tail block)
__global__ void k_dw_nemb(const float* __restrict__ z, const float* __restrict__ ema_w,
                          const int* __restrict__ counts, const int* __restrict__ offsets,
                          const int* __restrict__ buckets, const float* __restrict__ ncs,
                          const float* __restrict__ ntot_p, const float* __restrict__ losspart,
                          float* __restrict__ nemaw, float* __restrict__ nemb,
                          float* __restrict__ loss_out) {
    __shared__ float lred[4];
    if (blockIdx.x == K_CODES) {          // loss finalize
        const int t = threadIdx.x;        // 256
        float s = 0.0f;
        for (int i = t; i < 8192; i += 256) s += losspart[i];
#pragma unroll
        for (int off = 32; off > 0; off >>= 1) s += __shfl_down(s, off, 64);
        if ((t & 63) == 0) lred[t >> 6] = s;
        __syncthreads();
        if (t == 0)
            *loss_out = 0.25f * ((lred[0] + lred[1]) + (lred[2] + lred[3])) / 8388608.0f;
        return;
    }
    const int code = blockIdx.x;
    const int d    = threadIdx.x;         // 256 = DIM
    const int cnt  = counts[code];
    const int off  = offsets[code];
    float acc = 0.0f;
    for (int it = 0; it < cnt; ++it)
        acc += z[(size_t)buckets[off + it] * DIM + d];
    const float wv = fmaf(0.99f, ema_w[(size_t)code * DIM + d], 0.01f * acc);
    nemaw[(size_t)code * DIM + d] = wv;
    const float n  = *ntot_p;
    const float cs = (ncs[code] + 1e-5f) * (n / (n + (float)K_CODES * 1e-5f));
    nemb[(size_t)code * DIM + d] = wv / cs;
}

// ================================================================ fp32 fallback path (round-1 verified)
#define BM   64
#define BN   128
#define LSTR 36

__global__ void k_esq_zero_fb(const float* __restrict__ emb, float* __restrict__ esq,
                              float* __restrict__ zbuf) {
    const int gid  = blockIdx.x * blockDim.x + threadIdx.x;
    if (gid < K_CODES + 2) zbuf[gid] = 0.0f;
    const int code = gid >> 6;
    const int lane = gid & 63;
    float4 v = ((const float4*)emb)[code * 64 + lane];
    float s = fmaf(v.x, v.x, fmaf(v.y, v.y, fmaf(v.z, v.z, v.w * v.w)));
#pragma unroll
    for (int off = 32; off > 0; off >>= 1) s += __shfl_down(s, off, 64);
    if (lane == 0) esq[code] = s;
}

__global__ void k_init_nemaw_fb(const float* __restrict__ ema_w, float* __restrict__ out) {
    const int i = blockIdx.x * blockDim.x + threadIdx.x;
    float4 v = ((const float4*)ema_w)[i];
    ((float4*)out)[i] = make_float4(0.99f * v.x, 0.99f * v.y, 0.99f * v.z, 0.99f * v.w);
}

__global__ __launch_bounds__(256, 2) void k_argmin_fb(
        const float* __restrict__ z, const float* __restrict__ emb,
        const float* __restrict__ esq, int* __restrict__ idx_i, float* __restrict__ idx_f) {
    __shared__ float z_s[BM * LSTR];
    __shared__ float e_s[BN * LSTR];
    const int t = threadIdx.x, tx = t & 15, ty = t >> 4;
    const int row0 = blockIdx.x * BM;
    float best[4]; int bidx[4];
#pragma unroll
    for (int r = 0; r < 4; ++r) { best[r] = FLT_MAX; bidx[r] = 0; }
    for (int k0 = 0; k0 < K_CODES; k0 += BN) {
        float acc[4][8];
#pragma unroll
        for (int r = 0; r < 4; ++r)
#pragma unroll
            for (int c = 0; c < 8; ++c) acc[r][c] = 0.0f;
        for (int d0 = 0; d0 < DIM; d0 += 32) {
            __syncthreads();
#pragma unroll
            for (int i = 0; i < 2; ++i) {
                int f = i * 256 + t, r = f >> 3, c4 = (f & 7) << 2;
                *(float4*)&z_s[r * LSTR + c4] =
                    *(const float4*)(z + (size_t)(row0 + r) * DIM + d0 + c4);
            }
#pragma unroll
            for (int i = 0; i < 4; ++i) {
                int f = i * 256 + t, c = f >> 3, c4 = (f & 7) << 2;
                *(float4*)&e_s[c * LSTR + c4] =
                    *(const float4*)(emb + (size_t)(k0 + c) * DIM + d0 + c4);
            }
            __syncthreads();
#pragma unroll
            for (int dd = 0; dd < 32; dd += 4) {
                float4 a[4], b[8];
#pragma unroll
                for (int j = 0; j < 4; ++j)
                    a[j] = *(const float4*)&z_s[(ty * 4 + j) * LSTR + dd];
#pragma unroll
                for (int j = 0; j < 8; ++j)
                    b[j] = *(const float4*)&e_s[(tx + 16 * j) * LSTR + dd];
#pragma unroll
                for (int r = 0; r < 4; ++r)
#pragma unroll
                    for (int c = 0; c < 8; ++c) {
                        acc[r][c] = fmaf(a[r].x, b[c].x, acc[r][c]);
                        acc[r][c] = fmaf(a[r].y, b[c].y, acc[r][c]);
                        acc[r][c] = fmaf(a[r].z, b[c].z, acc[r][c]);
                        acc[r][c] = fmaf(a[r].w, b[c].w, acc[r][c]);
                    }
            }
        }
#pragma unroll
        for (int c = 0; c < 8; ++c) {
            const int code = k0 + tx + 16 * c;
            const float es = esq[code];
#pragma unroll
            for (int r = 0; r < 4; ++r) {
                float s = fmaf(-2.0f, acc[r][c], es);
                if (s < best[r] || (s == best[r] && code < bidx[r])) {
                    best[r] = s; bidx[r] = code;
                }
            }
        }
    }
    __syncthreads();
    float* rv = e_s; int* ri = (int*)z_s;
#pragma unroll
    for (int r = 0; r < 4; ++r) {
        rv[(ty * 4 + r) * 16 + tx] = best[r];
        ri[(ty * 4 + r) * 16 + tx] = bidx[r];
    }
    __syncthreads();
    if (t < 64) {
        float mv = rv[t * 16]; int mi = ri[t * 16];
#pragma unroll
        for (int i = 1; i < 16; ++i) {
            float v = rv[t * 16 + i]; int vi = ri[t * 16 + i];
            if (v < mv || (v == mv && vi < mi)) { mv = v; mi = vi; }
        }
        idx_i[row0 + t] = mi;
        idx_f[row0 + t] = (float)mi;
    }
}

__global__ void k_gather_fb(const float* __restrict__ z, const float* __restrict__ emb,
                            const int* __restrict__ idx_i, float* __restrict__ zq,
                            float* __restrict__ nemaw, float* __restrict__ counts,
                            float* __restrict__ loss) {
    const int gid  = blockIdx.x * blockDim.x + threadIdx.x;
    const int row  = gid >> 6;
    const int lane = gid & 63;
    const int code = idx_i[row];
    float4 zv = ((const float4*)z)[row * 64 + lane];
    float4 ev = ((const float4*)emb)[(size_t)code * 64 + lane];
    float4 o = make_float4(zv.x + (ev.x - zv.x), zv.y + (ev.y - zv.y),
                           zv.z + (ev.z - zv.z), zv.w + (ev.w - zv.w));
    ((float4*)zq)[row * 64 + lane] = o;
    float dx = ev.x - zv.x, dy = ev.y - zv.y, dz = ev.z - zv.z, dw = ev.w - zv.w;
    float s = fmaf(dx, dx, fmaf(dy, dy, fmaf(dz, dz, dw * dw)));
#pragma unroll
    for (int off = 32; off > 0; off >>= 1) s += __shfl_down(s, off, 64);
    if (lane == 0) { atomicAdd(loss, s); atomicAdd(&counts[code], 1.0f); }
    float* base = nemaw + (size_t)code * DIM + lane * 4;
    atomicAdd(base + 0, 0.01f * zv.x);
    atomicAdd(base + 1, 0.01f * zv.y);
    atomicAdd(base + 2, 0.01f * zv.z);
    atomicAdd(base + 3, 0.01f * zv.w);
}

__global__ void k_ncs_fb(const float* __restrict__ ema_cs, const float* __restrict__ counts,
                         float* __restrict__ ncs_out, float* __restrict__ ntot,
                         const float* __restrict__ loss_in, float* __restrict__ loss_out) {
    __shared__ float red[16];
    const int t = threadIdx.x;
    float s = 0.0f;
    for (int i = t; i < K_CODES; i += 1024) {
        float v = fmaf(0.99f, ema_cs[i], 0.01f * counts[i]);
        ncs_out[i] = v; s += v;
    }
#pragma unroll
    for (int off = 32; off > 0; off >>= 1) s += __shfl_down(s, off, 64);
    if ((t & 63) == 0) red[t >> 6] = s;
    __syncthreads();
    if (t < 16) {
        float v = red[t];
#pragma unroll
        for (int off = 8; off > 0; off >>= 1) v += __shfl_down(v, off, 16);
        if (t == 0) { *ntot = v; *loss_out = 0.25f * (*loss_in) / 8388608.0f; }
    }
}

__global__ void k_nemb_fb(const float* __restrict__ nemaw, const float* __restrict__ ncs,
                          const float* __restrict__ ntot_p, float* __restrict__ nemb) {
    const int i4 = blockIdx.x * blockDim.x + threadIdx.x;
    const int k  = i4 >> 6;
    const float n   = *ntot_p;
    const float inv = n / (n + (float)K_CODES * 1e-5f);
    const float cs  = (ncs[k] + 1e-5f) * inv;
    float4 wv = ((const float4*)nemaw)[i4];
    ((float4*)nemb)[i4] = make_float4(wv.x / cs, wv.y / cs, wv.z / cs, wv.w / cs);
}

extern "C" void kernel_launch(void* const* d_in, const int* in_sizes, int n_in,
                              void* d_out, int out_size, void* d_ws, size_t ws_size,
                              hipStream_t stream) {
    const float* z      = (const float*)d_in[0];
    const float* emb    = (const float*)d_in[1];
    const float* ema_cs = (const float*)d_in[2];
    const float* ema_w  = (const float*)d_in[3];
    float* out = (float*)d_out;
    char* wsb = (char*)d_ws;

    // ---- MFMA-path workspace layout (bytes), total 43,417,616 (NCH=2 uses
    // only half of part_v/part_i but offsets kept from r3 layout)
    unsigned short* zcat    = (unsigned short*)wsb;                  // 33,554,432
    unsigned short* ecat    = (unsigned short*)(wsb + 33554432);     //  8,388,608
    float*          part_v  = (float*)(wsb + 41943040);              //    524,288
    int*            part_i  = (int*)  (wsb + 42467328);              //    524,288
    float*          esq     = (float*)(wsb + 42991616);              //     32,768
    int*            ws_idx  = (int*)  (wsb + 43024384);              //    131,072
    int*            counts  = (int*)  (wsb + 43155456);              //     32,768
    int*            cursor  = (int*)  (wsb + 43188224);              //     32,768 (contiguous w/ counts)
    int*            offsets = (int*)  (wsb + 43220992);              //     32,768
    int*            buckets = (int*)  (wsb + 43253760);              //    131,072
    float*          lpart   = (float*)(wsb + 43384832);              //     32,768
    float*          ws_loss = (float*)(wsb + 43417600);
    float*          ws_ntot = ws_loss + 1;

    if (ws_size >= (size_t)43417616) {
        // one-time opt-in for 128 KB dynamic LDS (default cap is 64 KB).
        // host-side attribute set, not stream-ordered: graph-capture safe.
        static bool lds_attr_set = false;
        if (!lds_attr_set) {
            (void)hipFuncSetAttribute((const void*)k_argmin_mfma,
                                      hipFuncAttributeMaxDynamicSharedMemorySize,
                                      LDS_BYTES);
            lds_attr_set = true;
        }
        k_prep       <<<10240, 256, 0, stream>>>(z, emb, zcat, ecat, esq, counts);
        k_argmin_mfma<<<dim3(NROWS / 256, NCH), 512, LDS_BYTES, stream>>>(
            zcat, ecat, esq, part_v, part_i);
        k_reduce_part<<<NROWS / 256, 256, 0, stream>>>(part_v, part_i, ws_idx,
                                                       out + O_IDX, counts);
        k_scan_ncs   <<<1, 1024, 0, stream>>>(counts, ema_cs, offsets,
                                              out + O_NCS, ws_ntot);
        k_zq         <<<NROWS / 4, 256, 0, stream>>>(z, emb, ws_idx, offsets, cursor,
                                                     buckets, out + O_ZQ, lpart);
        k_dw_nemb    <<<K_CODES + 1, 256, 0, stream>>>(z, ema_w, counts, offsets, buckets,
                                                       out + O_NCS, ws_ntot, lpart,
                                                       out + O_NEMAW, out + O_NEMB,
                                                       out + O_LOSS);
    } else {
        // small-ws fallback (round-1 verified fp32 path)
        int*   f_idx    = (int*)wsb;
        float* f_counts = (float*)(wsb + 131072);
        float* f_loss   = f_counts + K_CODES;
        float* f_ntot   = f_loss + 1;
        float* f_esq    = (float*)(wsb + 163856);
        k_esq_zero_fb  <<<2048, 256, 0, stream>>>(emb, f_esq, f_counts);
        k_init_nemaw_fb<<<2048, 256, 0, stream>>>(ema_w, out + O_NEMAW);
        k_argmin_fb    <<<NROWS / BM, 256, 0, stream>>>(z, emb, f_esq, f_idx, out + O_IDX);
        k_gather_fb    <<<NROWS / 4, 256, 0, stream>>>(z, emb, f_idx, out + O_ZQ,
                                                       out + O_NEMAW, f_counts, f_loss);
        k_ncs_fb       <<<1, 1024, 0, stream>>>(ema_cs, f_counts, out + O_NCS, f_ntot,
                                                f_loss, out + O_LOSS);
        k_nemb_fb      <<<2048, 256, 0, stream>>>(out + O_NEMAW, out + O_NCS, f_ntot,
                                                  out + O_NEMB);
    }
}

// Round 7
// 637.343 us; speedup vs baseline: 1.0733x; 1.0286x over previous
//
#include <hip/hip_runtime.h>
#include <cfloat>

// VQ-VAE vector quantizer. Round 12: r11's cycle model showed LDS reads
// (1156 cyc/KT) and MFMA (1242 cyc/KT) run fully SERIALIZED (2632 cyc/KT
// measured) because lgkmcnt(0) gates every MFMA on every read and 2 barriers
// per KT re-lockstep the waves. Fix: ONE barrier per KT (ring hazard is
// per-KT) + counted lgkmcnt chain interleaving read-issue with MFMA
// 4-clusters (DS returns are in-order per wave), sched_barrier(0) after
// each wait (rule #18). Same tile/ring/swizzle/staging as r11.
// N=32768 rows, K=8192 codes, D=256.
#define K_CODES 8192
#define DIM     256
#define NROWS   32768

// d_out float offsets (outputs concatenated in reference return order)
#define O_ZQ    0
#define O_LOSS  8388608
#define O_IDX   8388609
#define O_NEMB  8421377
#define O_NCS   10518529
#define O_NEMAW 10526721

// ---- MFMA path params
#define NCH          2                    // code chunks
#define CODES_PER_CH (K_CODES / NCH)      // 4096
#define NT_TILES     (CODES_PER_CH / 256) // 16
#define KT_PER_NT    24                   // virtual K 768 / BK 32
#define KT_TOTAL     (NT_TILES * KT_PER_NT) // 384
#define LDS_BYTES    131072               // 4 ring buffers x 32 KB

typedef __attribute__((ext_vector_type(8))) short short8;
typedef __attribute__((ext_vector_type(4))) float floatx4;

__device__ __forceinline__ unsigned short f2bf_rne(float x) {
    unsigned u = __float_as_uint(x);
    u += 0x7fffu + ((u >> 16) & 1u);
    return (unsigned short)(u >> 16);
}
__device__ __forceinline__ float bf2f(unsigned short h) {
    return __uint_as_float(((unsigned)h) << 16);
}
__device__ __forceinline__ void async16(const void* g, void* l) {
    __builtin_amdgcn_global_load_lds(
        (const __attribute__((address_space(1))) void*)g,
        (__attribute__((address_space(3))) void*)l, 16, 0, 0);
}
__device__ __forceinline__ unsigned ldsaddr(const void* p) {
    return (unsigned)(unsigned long long)
        (const __attribute__((address_space(3))) void*)p;
}
// inline-asm LDS read: invisible to alias analysis; RAW protection is the
// counted lgkmcnt chain + sched_barrier(0) fences below (guide rule #18).
#define DSR(dst, addr, off)                                                     \
    asm volatile("ds_read_b128 %0, %1 offset:" #off : "=v"(dst) : "v"(addr))
#define WAITL(n)                                                                \
    do {                                                                        \
        asm volatile("s_waitcnt lgkmcnt(" #n ")" ::: "memory");                 \
        __builtin_amdgcn_sched_barrier(0);                                      \
    } while (0)

// ---------------------------------------------------------------- fused convert: z & emb -> {hi,lo} bf16 + |e|^2 + zero
__global__ void k_prep(const float* __restrict__ z, const float* __restrict__ emb,
                       unsigned short* __restrict__ zcat, unsigned short* __restrict__ ecat,
                       float* __restrict__ esq, int* __restrict__ zero16k) {
    const int b = blockIdx.x;
    if (b < 8192) {
        const int i = b * 256 + threadIdx.x;         // float4 idx, 2,097,152
        const int row = i >> 6;
        const int col = (i & 63) << 2;
        float4 v = ((const float4*)z)[i];
        // fold -2 into z: bf16(-2z) == -2*bf16(z) exactly (pow2 scale)
        float nx = -2.0f * v.x, ny = -2.0f * v.y, nz = -2.0f * v.z, nw = -2.0f * v.w;
        ushort4 h, l;
        h.x = f2bf_rne(nx); l.x = f2bf_rne(nx - bf2f(h.x));
        h.y = f2bf_rne(ny); l.y = f2bf_rne(ny - bf2f(h.y));
        h.z = f2bf_rne(nz); l.z = f2bf_rne(nz - bf2f(h.z));
        h.w = f2bf_rne(nw); l.w = f2bf_rne(nw - bf2f(h.w));
        *(ushort4*)&zcat[(size_t)row * 512 + col]       = h;
        *(ushort4*)&zcat[(size_t)row * 512 + 256 + col] = l;
    } else {
        const int gid  = (b - 8192) * 256 + threadIdx.x;  // 0..524287
        if (gid < 2 * K_CODES) zero16k[gid] = 0;          // counts + cursor
        const int code = gid >> 6;
        const int lane = gid & 63;
        const int col  = lane << 2;
        float4 v = ((const float4*)emb)[code * 64 + lane];
        ushort4 h, l;
        h.x = f2bf_rne(v.x); l.x = f2bf_rne(v.x - bf2f(h.x));
        h.y = f2bf_rne(v.y); l.y = f2bf_rne(v.y - bf2f(h.y));
        h.z = f2bf_rne(v.z); l.z = f2bf_rne(v.z - bf2f(h.z));
        h.w = f2bf_rne(v.w); l.w = f2bf_rne(v.w - bf2f(h.w));
        *(ushort4*)&ecat[(size_t)code * 512 + col]       = h;
        *(ushort4*)&ecat[(size_t)code * 512 + 256 + col] = l;
        float s = fmaf(v.x, v.x, fmaf(v.y, v.y, fmaf(v.z, v.z, v.w * v.w)));
#pragma unroll
        for (int off = 32; off > 0; off >>= 1) s += __shfl_down(s, off, 64);
        if (lane == 0) esq[code] = s;
    }
}

// ---------------------------------------------------------------- MFMA argmin GEMM (virtual K=768, BK=32, 256x256 tile)
// score(n,k) = esq[k] + dot(zcat_n, ecat_k segs), zcat encodes -2z.
// A segs {hi,hi,lo}: off_a=(k0&255)|((k0&512)>>1); B segs {hi,lo,hi}: off_b=k0&511.
// 8 waves (2M x 4N); wave tile 128x64; acc 8x4 of 16x16x32 (128 AGPRs).
// Ring of 4 LDS buffers; KT g in buf g&3; during KT g stage KT g+3.
// Per KT: [vmcnt(8) gate][ONE s_barrier][stage 4x async16][12 ds_read +
// 8 MFMA 4-clusters interleaved via counted lgkmcnt chain]. LDS reads of
// cluster c+1.. stream on the LDS pipe while cluster c's MFMAs execute.
// LDS layout per buffer: A 256x64B then B 256x64B; logical chunk c of row R
// at physical c ^ ((R>>1)&3) (conflict-free). Stage pre-swizzles the GLOBAL
// source (linear LDS dest per global_load_lds).
__global__ __launch_bounds__(512, 2) void k_argmin_mfma(
        const unsigned short* __restrict__ zcat, const unsigned short* __restrict__ ecat,
        const float* __restrict__ esq,
        float* __restrict__ part_v, int* __restrict__ part_i) {
    extern __shared__ __align__(16) unsigned short s_all[];
    const int t    = threadIdx.x;        // 0..511
    const int w    = t >> 6;             // 0..7
    const int lane = t & 63;
    const int quad = lane >> 4;
    const int m    = lane & 15;
    const int wr   = w >> 2;             // 0..1  (row half)
    const int wc   = w & 3;              // 0..3  (code quarter)
    const int row0   = blockIdx.x * 256;
    const int cbase0 = blockIdx.y * CODES_PER_CH;

    // staging geometry: per KT, A = 1024 16B slots (256 rows x 4 chunks),
    // B same. 512 threads x 2 loads each per half (q=1 is +128 rows: same
    // chunk and same swizzle since 128 rows == 0 mod the (R>>1)&3 key).
    const int prow = t >> 2;             // 0..127
    const int pch  = t & 3;
    const int lc   = pch ^ ((prow >> 1) & 3);
    const unsigned short* aSrc = zcat + (size_t)(row0 + prow) * 512 + lc * 8;
    const unsigned short* bSrc = ecat + (size_t)(cbase0 + prow) * 512 + lc * 8;
    const int dstU = prow * 32 + pch * 8;   // ushort offset within region

    // fragment-read addresses (bytes): row stride 64 B, chunk swizzle
    // physical chunk = quad ^ ((m>>1)&3) (kk-invariant, matches staging key)
    const int xo2 = (quad ^ ((m >> 1) & 3)) << 4;
    const unsigned lb = ldsaddr(s_all);
    const unsigned aRdTB = lb + (unsigned)((wr * 128 + m) * 64 + xo2);
    const unsigned bRdTB = lb + 16384u + (unsigned)((wc * 64 + m) * 64 + xo2);

    float    best_v[32];
    unsigned best_p[8];     // per i: 4 reg-slots x 8-bit candidate (nt*4+j)
#pragma unroll
    for (int r = 0; r < 32; ++r) best_v[r] = FLT_MAX;
#pragma unroll
    for (int i = 0; i < 8; ++i) best_p[i] = 0u;

    // prologue: stage KT 0,1,2 into ring bufs 0,1,2; es for nt=0
#pragma unroll
    for (int G = 0; G < 3; ++G) {
        const int k0   = G * 32;
        const int offA = (k0 & 255) | ((k0 & 512) >> 1);
        const int offB = k0 & 511;
        unsigned short* dA = s_all + G * 16384 + dstU;
        async16(aSrc + offA, dA);
        async16(aSrc + 65536 + offA, dA + 4096);
        async16(bSrc + offB, dA + 8192);
        async16(bSrc + 65536 + offB, dA + 12288);
    }
    float es[4];
#pragma unroll
    for (int j = 0; j < 4; ++j) es[j] = esq[cbase0 + wc * 64 + j * 16 + m];

#define CL(iacc, areg)                                                          \
    do {                                                                        \
        acc[iacc][0] = __builtin_amdgcn_mfma_f32_16x16x32_bf16(                 \
            areg, bf[0], acc[iacc][0], 0, 0, 0);                                \
        acc[iacc][1] = __builtin_amdgcn_mfma_f32_16x16x32_bf16(                 \
            areg, bf[1], acc[iacc][1], 0, 0, 0);                                \
        acc[iacc][2] = __builtin_amdgcn_mfma_f32_16x16x32_bf16(                 \
            areg, bf[2], acc[iacc][2], 0, 0, 0);                                \
        acc[iacc][3] = __builtin_amdgcn_mfma_f32_16x16x32_bf16(                 \
            areg, bf[3], acc[iacc][3], 0, 0, 0);                                \
    } while (0)

    for (int nt = 0; nt < NT_TILES; ++nt) {
        floatx4 acc[8][4];
#pragma unroll
        for (int j = 0; j < 4; ++j) {
            const float e = es[j];
#pragma unroll
            for (int i = 0; i < 8; ++i) acc[i][j] = (floatx4){e, e, e, e};
        }

#pragma unroll 1
        for (int kk = 0; kk < KT_PER_NT; ++kk) {
            const int g = nt * KT_PER_NT + kk;
            // entry gate: stage(g) landed (oldest outstanding); stages of
            // g+1,g+2 (8 loads) stay in flight across the barrier.
            if (g < KT_TOTAL - 2)
                asm volatile("s_waitcnt vmcnt(8)" ::: "memory");
            else if (g == KT_TOTAL - 2)
                asm volatile("s_waitcnt vmcnt(4)" ::: "memory");
            else
                asm volatile("s_waitcnt vmcnt(0)" ::: "memory");
            __builtin_amdgcn_s_barrier();       // all waves done with KT g-1
            __builtin_amdgcn_sched_barrier(0);

            // stage KT g+3 (overwrites buf (g-1)&3: safe post-barrier)
            const int G = g + 3;
            if (G < KT_TOTAL) {
                const int ntS = G / KT_PER_NT;
                const int k0  = (G - ntS * KT_PER_NT) * 32;
                const unsigned short* sA = aSrc + ((k0 & 255) | ((k0 & 512) >> 1));
                const unsigned short* sB = bSrc + (size_t)ntS * 131072 + (k0 & 511);
                unsigned short* dD = s_all + (G & 3) * 16384 + dstU;
                async16(sA, dD);
                async16(sA + 65536, dD + 4096);
                async16(sB, dD + 8192);
                async16(sB + 65536, dD + 12288);
            }
            const unsigned bub   = (unsigned)((g & 3) << 15);
            const unsigned addrA = aRdTB + bub;
            const unsigned addrB = bRdTB + bub;

            short8 af[4], bf[4];
            // issue B then A rows 0-3; interleave MFMA clusters with the
            // remaining reads via counted lgkmcnt (DS returns in-order).
            DSR(bf[0], addrB, 0);    DSR(bf[1], addrB, 1024);
            DSR(bf[2], addrB, 2048); DSR(bf[3], addrB, 3072);
            DSR(af[0], addrA, 0);    DSR(af[1], addrA, 1024);
            DSR(af[2], addrA, 2048); DSR(af[3], addrA, 3072);
            __builtin_amdgcn_s_setprio(1);
            WAITL(3); CL(0, af[0]);                 // bf0-3 + af0 landed
            WAITL(2); CL(1, af[1]);
            WAITL(1); CL(2, af[2]);
            DSR(af[0], addrA, 4096);                // rows 4-6 re-issued
            DSR(af[1], addrA, 5120);
            DSR(af[2], addrA, 6144);
            WAITL(3); CL(3, af[3]);                 // old af3 landed
            DSR(af[3], addrA, 7168);                // row 7
            WAITL(3); CL(4, af[0]);                 // row4 landed
            WAITL(2); CL(5, af[1]);
            WAITL(1); CL(6, af[2]);
            WAITL(0); CL(7, af[3]);
            __builtin_amdgcn_s_setprio(0);
        }
        // epilogue: acc IS the score. codes ascend in (nt,j): strict < =
        // first-min. Register-only; in-flight stages keep streaming.
#pragma unroll
        for (int j = 0; j < 4; ++j) {
            const unsigned cand = (unsigned)(nt * 4 + j);   // 6 bits
#pragma unroll
            for (int i = 0; i < 8; ++i)
#pragma unroll
                for (int reg = 0; reg < 4; ++reg) {
                    const float s = acc[i][j][reg];
                    const int r = i * 4 + reg;
                    if (s < best_v[r]) {
                        best_v[r] = s;
                        best_p[i] = (best_p[i] & ~(255u << (reg * 8))) | (cand << (reg * 8));
                    }
                }
        }
        if (nt + 1 < NT_TILES) {    // es prefetch for next code tile
#pragma unroll
            for (int j = 0; j < 4; ++j)
                es[j] = esq[cbase0 + (nt + 1) * 256 + wc * 64 + j * 16 + m];
        }
    }
#undef CL
    // reconstruct codes, butterfly across the 16 lanes sharing each row
    __syncthreads();               // all staging drained (last KT gated vmcnt 0)
    float* redv = (float*)s_all;            // [256][4] floats (4 KB)
    int*   redi = (int*)(s_all + 2048);     // [256][4] ints, disjoint (4 KB)
#pragma unroll
    for (int i = 0; i < 8; ++i)
#pragma unroll
        for (int reg = 0; reg < 4; ++reg) {
            const int r = i * 4 + reg;
            const unsigned b = (best_p[i] >> (reg * 8)) & 255u;
            float v  = best_v[r];
            int   bi = cbase0 + (int)(b >> 2) * 256 + wc * 64 + (int)(b & 3) * 16 + m;
#pragma unroll
            for (int off = 1; off < 16; off <<= 1) {
                const float ov = __shfl_xor(v, off, 64);
                const int   oi = __shfl_xor(bi, off, 64);
                if (ov < v || (ov == v && oi < bi)) { v = ov; bi = oi; }
            }
            if (m == 0) {
                const int rl = wr * 128 + i * 16 + quad * 4 + reg;
                redv[rl * 4 + wc] = v;
                redi[rl * 4 + wc] = bi;
            }
        }
    __syncthreads();
    if (t < 256) {
        float v = redv[t * 4]; int bi = redi[t * 4];
#pragma unroll
        for (int c = 1; c < 4; ++c) {
            const float v2 = redv[t * 4 + c];
            const int   i2 = redi[t * 4 + c];
            if (v2 < v || (v2 == v && i2 < bi)) { v = v2; bi = i2; }
        }
        const size_t o = (size_t)blockIdx.y * NROWS + blockIdx.x * 256 + t;
        part_v[o] = v;
        part_i[o] = bi;
    }
}

// ---------------------------------------------------------------- merge partials + histogram
__global__ void k_reduce_part(const float* __restrict__ pv, const int* __restrict__ pi,
                              int* __restrict__ idx_i, float* __restrict__ idx_f,
                              int* __restrict__ counts) {
    const int r = blockIdx.x * blockDim.x + threadIdx.x;
    float v = pv[r]; int bi = pi[r];
#pragma unroll
    for (int c = 1; c < NCH; ++c) {
        const float v2 = pv[(size_t)c * NROWS + r];
        const int   i2 = pi[(size_t)c * NROWS + r];
        if (v2 < v || (v2 == v && i2 < bi)) { v = v2; bi = i2; }
    }
    idx_i[r] = bi;
    idx_f[r] = (float)bi;
    atomicAdd(&counts[bi], 1);
}

// ---------------------------------------------------------------- scan + new_cluster_size + n  (1 block, 1024 thr)
__global__ void k_scan_ncs(const int* __restrict__ counts, const float* __restrict__ ema_cs,
                           int* __restrict__ offsets, float* __restrict__ ncs_out,
                           float* __restrict__ ntot) {
    __shared__ int   wsum[16];
    __shared__ float red[16];
    const int t = threadIdx.x;
    const int lane = t & 63, w = t >> 6;
    int c[8]; int s = 0; float fs = 0.0f;
#pragma unroll
    for (int u = 0; u < 8; ++u) {
        c[u] = counts[t * 8 + u]; s += c[u];
        const float v = fmaf(0.99f, ema_cs[t * 8 + u], 0.01f * (float)c[u]);
        ncs_out[t * 8 + u] = v;
        fs += v;
    }
    int inc = s;
#pragma unroll
    for (int off = 1; off < 64; off <<= 1) {
        const int n = __shfl_up(inc, off, 64);
        if (lane >= off) inc += n;
    }
#pragma unroll
    for (int off = 32; off > 0; off >>= 1) fs += __shfl_down(fs, off, 64);
    if (lane == 63) wsum[w] = inc;
    if (lane == 0)  red[w]  = fs;
    __syncthreads();
    if (t < 16) {
        int v = wsum[t];
#pragma unroll
        for (int off = 1; off < 16; off <<= 1) {
            const int n = __shfl_up(v, off, 64);
            if (t >= off) v += n;
        }
        wsum[t] = v;
        float fv = red[t];
#pragma unroll
        for (int off = 8; off > 0; off >>= 1) fv += __shfl_down(fv, off, 16);
        if (t == 0) *ntot = fv;
    }
    __syncthreads();
    int base = (w > 0 ? wsum[w - 1] : 0) + (inc - s);
#pragma unroll
    for (int u = 0; u < 8; ++u) { offsets[t * 8 + u] = base; base += c[u]; }
}

// ---------------------------------------------------------------- zq + loss partials + bucket scatter
__global__ void k_zq(const float* __restrict__ z, const float* __restrict__ emb,
                     const int* __restrict__ idx_i, const int* __restrict__ offsets,
                     int* __restrict__ cursor, int* __restrict__ buckets,
                     float* __restrict__ zq, float* __restrict__ losspart) {
    __shared__ float lred[4];
    const int t = threadIdx.x;
    const int wr = t >> 6, lane = t & 63;
    const int row = blockIdx.x * 4 + wr;
    const int code = idx_i[row];
    float4 zv = ((const float4*)z)[row * 64 + lane];
    float4 ev = ((const float4*)emb)[(size_t)code * 64 + lane];
    float4 o = make_float4(zv.x + (ev.x - zv.x), zv.y + (ev.y - zv.y),
                           zv.z + (ev.z - zv.z), zv.w + (ev.w - zv.w));
    ((float4*)zq)[row * 64 + lane] = o;
    float dx = ev.x - zv.x, dy = ev.y - zv.y, dz = ev.z - zv.z, dw = ev.w - zv.w;
    float s = fmaf(dx, dx, fmaf(dy, dy, fmaf(dz, dz, dw * dw)));
#pragma unroll
    for (int off = 32; off > 0; off >>= 1) s += __shfl_down(s, off, 64);
    if (lane == 0) {
        lred[wr] = s;
        const int pos = atomicAdd(&cursor[code], 1);
        buckets[offsets[code] + pos] = row;
    }
    __syncthreads();
    if (t == 0) losspart[blockIdx.x] = (lred[0] + lred[1]) + (lred[2] + lred[3]);
}

// ---------------------------------------------------------------- dw + new_ema_w + new_embedding (+loss tail block)
__global__ void k_dw_nemb(const float* __restrict__ z, const float* __restrict__ ema_w,
                          const int* __restrict__ counts, const int* __restrict__ offsets,
                          const int* __restrict__ buckets, const float* __restrict__ ncs,
                          const float* __restrict__ ntot_p, const float* __restrict__ losspart,
                          float* __restrict__ nemaw, float* __restrict__ nemb,
                          float* __restrict__ loss_out) {
    __shared__ float lred[4];
    if (blockIdx.x == K_CODES) {          // loss finalize
        const int t = threadIdx.x;        // 256
        float s = 0.0f;
        for (int i = t; i < 8192; i += 256) s += losspart[i];
#pragma unroll
        for (int off = 32; off > 0; off >>= 1) s += __shfl_down(s, off, 64);
        if ((t & 63) == 0) lred[t >> 6] = s;
        __syncthreads();
        if (t == 0)
            *loss_out = 0.25f * ((lred[0] + lred[1]) + (lred[2] + lred[3])) / 8388608.0f;
        return;
    }
    const int code = blockIdx.x;
    const int d    = threadIdx.x;         // 256 = DIM
    const int cnt  = counts[code];
    const int off  = offsets[code];
    float acc = 0.0f;
    for (int it = 0; it < cnt; ++it)
        acc += z[(size_t)buckets[off + it] * DIM + d];
    const float wv = fmaf(0.99f, ema_w[(size_t)code * DIM + d], 0.01f * acc);
    nemaw[(size_t)code * DIM + d] = wv;
    const float n  = *ntot_p;
    const float cs = (ncs[code] + 1e-5f) * (n / (n + (float)K_CODES * 1e-5f));
    nemb[(size_t)code * DIM + d] = wv / cs;
}

// ================================================================ fp32 fallback path (round-1 verified)
#define BM   64
#define BN   128
#define LSTR 36

__global__ void k_esq_zero_fb(const float* __restrict__ emb, float* __restrict__ esq,
                              float* __restrict__ zbuf) {
    const int gid  = blockIdx.x * blockDim.x + threadIdx.x;
    if (gid < K_CODES + 2) zbuf[gid] = 0.0f;
    const int code = gid >> 6;
    const int lane = gid & 63;
    float4 v = ((const float4*)emb)[code * 64 + lane];
    float s = fmaf(v.x, v.x, fmaf(v.y, v.y, fmaf(v.z, v.z, v.w * v.w)));
#pragma unroll
    for (int off = 32; off > 0; off >>= 1) s += __shfl_down(s, off, 64);
    if (lane == 0) esq[code] = s;
}

__global__ void k_init_nemaw_fb(const float* __restrict__ ema_w, float* __restrict__ out) {
    const int i = blockIdx.x * blockDim.x + threadIdx.x;
    float4 v = ((const float4*)ema_w)[i];
    ((float4*)out)[i] = make_float4(0.99f * v.x, 0.99f * v.y, 0.99f * v.z, 0.99f * v.w);
}

__global__ __launch_bounds__(256, 2) void k_argmin_fb(
        const float* __restrict__ z, const float* __restrict__ emb,
        const float* __restrict__ esq, int* __restrict__ idx_i, float* __restrict__ idx_f) {
    __shared__ float z_s[BM * LSTR];
    __shared__ float e_s[BN * LSTR];
    const int t = threadIdx.x, tx = t & 15, ty = t >> 4;
    const int row0 = blockIdx.x * BM;
    float best[4]; int bidx[4];
#pragma unroll
    for (int r = 0; r < 4; ++r) { best[r] = FLT_MAX; bidx[r] = 0; }
    for (int k0 = 0; k0 < K_CODES; k0 += BN) {
        float acc[4][8];
#pragma unroll
        for (int r = 0; r < 4; ++r)
#pragma unroll
            for (int c = 0; c < 8; ++c) acc[r][c] = 0.0f;
        for (int d0 = 0; d0 < DIM; d0 += 32) {
            __syncthreads();
#pragma unroll
            for (int i = 0; i < 2; ++i) {
                int f = i * 256 + t, r = f >> 3, c4 = (f & 7) << 2;
                *(float4*)&z_s[r * LSTR + c4] =
                    *(const float4*)(z + (size_t)(row0 + r) * DIM + d0 + c4);
            }
#pragma unroll
            for (int i = 0; i < 4; ++i) {
                int f = i * 256 + t, c = f >> 3, c4 = (f & 7) << 2;
                *(float4*)&e_s[c * LSTR + c4] =
                    *(const float4*)(emb + (size_t)(k0 + c) * DIM + d0 + c4);
            }
            __syncthreads();
#pragma unroll
            for (int dd = 0; dd < 32; dd += 4) {
                float4 a[4], b[8];
#pragma unroll
                for (int j = 0; j < 4; ++j)
                    a[j] = *(const float4*)&z_s[(ty * 4 + j) * LSTR + dd];
#pragma unroll
                for (int j = 0; j < 8; ++j)
                    b[j] = *(const float4*)&e_s[(tx + 16 * j) * LSTR + dd];
#pragma unroll
                for (int r = 0; r < 4; ++r)
#pragma unroll
                    for (int c = 0; c < 8; ++c) {
                        acc[r][c] = fmaf(a[r].x, b[c].x, acc[r][c]);
                        acc[r][c] = fmaf(a[r].y, b[c].y, acc[r][c]);
                        acc[r][c] = fmaf(a[r].z, b[c].z, acc[r][c]);
                        acc[r][c] = fmaf(a[r].w, b[c].w, acc[r][c]);
                    }
            }
        }
#pragma unroll
        for (int c = 0; c < 8; ++c) {
            const int code = k0 + tx + 16 * c;
            const float es = esq[code];
#pragma unroll
            for (int r = 0; r < 4; ++r) {
                float s = fmaf(-2.0f, acc[r][c], es);
                if (s < best[r] || (s == best[r] && code < bidx[r])) {
                    best[r] = s; bidx[r] = code;
                }
            }
        }
    }
    __syncthreads();
    float* rv = e_s; int* ri = (int*)z_s;
#pragma unroll
    for (int r = 0; r < 4; ++r) {
        rv[(ty * 4 + r) * 16 + tx] = best[r];
        ri[(ty * 4 + r) * 16 + tx] = bidx[r];
    }
    __syncthreads();
    if (t < 64) {
        float mv = rv[t * 16]; int mi = ri[t * 16];
#pragma unroll
        for (int i = 1; i < 16; ++i) {
            float v = rv[t * 16 + i]; int vi = ri[t * 16 + i];
            if (v < mv || (v == mv && vi < mi)) { mv = v; mi = vi; }
        }
        idx_i[row0 + t] = mi;
        idx_f[row0 + t] = (float)mi;
    }
}

__global__ void k_gather_fb(const float* __restrict__ z, const float* __restrict__ emb,
                            const int* __restrict__ idx_i, float* __restrict__ zq,
                            float* __restrict__ nemaw, float* __restrict__ counts,
                            float* __restrict__ loss) {
    const int gid  = blockIdx.x * blockDim.x + threadIdx.x;
    const int row  = gid >> 6;
    const int lane = gid & 63;
    const int code = idx_i[row];
    float4 zv = ((const float4*)z)[row * 64 + lane];
    float4 ev = ((const float4*)emb)[(size_t)code * 64 + lane];
    float4 o = make_float4(zv.x + (ev.x - zv.x), zv.y + (ev.y - zv.y),
                           zv.z + (ev.z - zv.z), zv.w + (ev.w - zv.w));
    ((float4*)zq)[row * 64 + lane] = o;
    float dx = ev.x - zv.x, dy = ev.y - zv.y, dz = ev.z - zv.z, dw = ev.w - zv.w;
    float s = fmaf(dx, dx, fmaf(dy, dy, fmaf(dz, dz, dw * dw)));
#pragma unroll
    for (int off = 32; off > 0; off >>= 1) s += __shfl_down(s, off, 64);
    if (lane == 0) { atomicAdd(loss, s); atomicAdd(&counts[code], 1.0f); }
    float* base = nemaw + (size_t)code * DIM + lane * 4;
    atomicAdd(base + 0, 0.01f * zv.x);
    atomicAdd(base + 1, 0.01f * zv.y);
    atomicAdd(base + 2, 0.01f * zv.z);
    atomicAdd(base + 3, 0.01f * zv.w);
}

__global__ void k_ncs_fb(const float* __restrict__ ema_cs, const float* __restrict__ counts,
                         float* __restrict__ ncs_out, float* __restrict__ ntot,
                         const float* __restrict__ loss_in, float* __restrict__ loss_out) {
    __shared__ float red[16];
    const int t = threadIdx.x;
    float s = 0.0f;
    for (int i = t; i < K_CODES; i += 1024) {
        float v = fmaf(0.99f, ema_cs[i], 0.01f * counts[i]);
        ncs_out[i] = v; s += v;
    }
#pragma unroll
    for (int off = 32; off > 0; off >>= 1) s += __shfl_down(s, off, 64);
    if ((t & 63) == 0) red[t >> 6] = s;
    __syncthreads();
    if (t < 16) {
        float v = red[t];
#pragma unroll
        for (int off = 8; off > 0; off >>= 1) v += __shfl_down(v, off, 16);
        if (t == 0) { *ntot = v; *loss_out = 0.25f * (*loss_in) / 8388608.0f; }
    }
}

__global__ void k_nemb_fb(const float* __restrict__ nemaw, const float* __restrict__ ncs,
                          const float* __restrict__ ntot_p, float* __restrict__ nemb) {
    const int i4 = blockIdx.x * blockDim.x + threadIdx.x;
    const int k  = i4 >> 6;
    const float n   = *ntot_p;
    const float inv = n / (n + (float)K_CODES * 1e-5f);
    const float cs  = (ncs[k] + 1e-5f) * inv;
    float4 wv = ((const float4*)nemaw)[i4];
    ((float4*)nemb)[i4] = make_float4(wv.x / cs, wv.y / cs, wv.z / cs, wv.w / cs);
}

extern "C" void kernel_launch(void* const* d_in, const int* in_sizes, int n_in,
                              void* d_out, int out_size, void* d_ws, size_t ws_size,
                              hipStream_t stream) {
    const float* z      = (const float*)d_in[0];
    const float* emb    = (const float*)d_in[1];
    const float* ema_cs = (const float*)d_in[2];
    const float* ema_w  = (const float*)d_in[3];
    float* out = (float*)d_out;
    char* wsb = (char*)d_ws;

    // ---- MFMA-path workspace layout (bytes), total 43,417,616 (NCH=2 uses
    // only half of part_v/part_i but offsets kept from r3 layout)
    unsigned short* zcat    = (unsigned short*)wsb;                  // 33,554,432
    unsigned short* ecat    = (unsigned short*)(wsb + 33554432);     //  8,388,608
    float*          part_v  = (float*)(wsb + 41943040);              //    524,288
    int*            part_i  = (int*)  (wsb + 42467328);              //    524,288
    float*          esq     = (float*)(wsb + 42991616);              //     32,768
    int*            ws_idx  = (int*)  (wsb + 43024384);              //    131,072
    int*            counts  = (int*)  (wsb + 43155456);              //     32,768
    int*            cursor  = (int*)  (wsb + 43188224);              //     32,768 (contiguous w/ counts)
    int*            offsets = (int*)  (wsb + 43220992);              //     32,768
    int*            buckets = (int*)  (wsb + 43253760);              //    131,072
    float*          lpart   = (float*)(wsb + 43384832);              //     32,768
    float*          ws_loss = (float*)(wsb + 43417600);
    float*          ws_ntot = ws_loss + 1;

    if (ws_size >= (size_t)43417616) {
        // one-time opt-in for 128 KB dynamic LDS (default cap is 64 KB).
        // host-side attribute set, not stream-ordered: graph-capture safe.
        static bool lds_attr_set = false;
        if (!lds_attr_set) {
            (void)hipFuncSetAttribute((const void*)k_argmin_mfma,
                                      hipFuncAttributeMaxDynamicSharedMemorySize,
                                      LDS_BYTES);
            lds_attr_set = true;
        }
        k_prep       <<<10240, 256, 0, stream>>>(z, emb, zcat, ecat, esq, counts);
        k_argmin_mfma<<<dim3(NROWS / 256, NCH), 512, LDS_BYTES, stream>>>(
            zcat, ecat, esq, part_v, part_i);
        k_reduce_part<<<NROWS / 256, 256, 0, stream>>>(part_v, part_i, ws_idx,
                                                       out + O_IDX, counts);
        k_scan_ncs   <<<1, 1024, 0, stream>>>(counts, ema_cs, offsets,
                                              out + O_NCS, ws_ntot);
        k_zq         <<<NROWS / 4, 256, 0, stream>>>(z, emb, ws_idx, offsets, cursor,
                                                     buckets, out + O_ZQ, lpart);
        k_dw_nemb    <<<K_CODES + 1, 256, 0, stream>>>(z, ema_w, counts, offsets, buckets,
                                                       out + O_NCS, ws_ntot, lpart,
                                                       out + O_NEMAW, out + O_NEMB,
                                                       out + O_LOSS);
    } else {
        // small-ws fallback (round-1 verified fp32 path)
        int*   f_idx    = (int*)wsb;
        float* f_counts = (float*)(wsb + 131072);
        float* f_loss   = f_counts + K_CODES;
        float* f_ntot   = f_loss + 1;
        float* f_esq    = (float*)(wsb + 163856);
        k_esq_zero_fb  <<<2048, 256, 0, stream>>>(emb, f_esq, f_counts);
        k_init_nemaw_fb<<<2048, 256, 0, stream>>>(ema_w, out + O_NEMAW);
        k_argmin_fb    <<<NROWS / BM, 256, 0, stream>>>(z, emb, f_esq, f_idx, out + O_IDX);
        k_gather_fb    <<<NROWS / 4, 256, 0, stream>>>(z, emb, f_idx, out + O_ZQ,
                                                       out + O_NEMAW, f_counts, f_loss);
        k_ncs_fb       <<<1, 1024, 0, stream>>>(ema_cs, f_counts, out + O_NCS, f_ntot,
                                                f_loss, out + O_LOSS);
        k_nemb_fb      <<<2048, 256, 0, stream>>>(out + O_NEMAW, out + O_NCS, f_ntot,
                                                  out + O_NEMB);
    }
}